// Round 10
// baseline (3105.115 us; speedup 1.0000x reference)
//
#include <hip/hip_runtime.h>

#define B 8
#define NOBJ 128
#define NATTR 4
#define T 12
#define MC 2048
#define E 128
#define IDD 64
#define AD 64
#define HD 256
#define C 2176

typedef short s16x8 __attribute__((ext_vector_type(8)));
typedef float f32x4 __attribute__((ext_vector_type(4)));

__device__ inline unsigned short f2b(float f) {
  union { float f; unsigned u; } v; v.f = f;
  unsigned r = v.u + 0x7FFFu + ((v.u >> 16) & 1u);
  return (unsigned short)(r >> 16);
}
__device__ inline float b2f(unsigned short u) {
  union { unsigned u; float f; } v; v.u = ((unsigned)u) << 16;
  return v.f;
}

// coherent (MALL-routed) accessors for the mid-step handoff only
__device__ __forceinline__ void st_coh_u64(unsigned long long* p, unsigned long long v) {
  __hip_atomic_store(p, v, __ATOMIC_RELAXED, __HIP_MEMORY_SCOPE_AGENT);
}
__device__ __forceinline__ void st_coh_u32(unsigned* p, unsigned v) {
  __hip_atomic_store(p, v, __ATOMIC_RELAXED, __HIP_MEMORY_SCOPE_AGENT);
}
__device__ __forceinline__ unsigned ld_coh_u32(const unsigned* p) {
  return __hip_atomic_load(p, __ATOMIC_RELAXED, __HIP_MEMORY_SCOPE_AGENT);
}

// LDS swizzles: XOR row bits into the 16B-slot index (conflict-free b128 access)
__device__ __forceinline__ int gidx(int r, int c) {   // g [64][128]
  return r * 128 + ((((c >> 3) ^ (r & 15)) << 3) | (c & 7));
}
__device__ __forceinline__ int hidx(int r, int c) {   // h [64][256]
  return r * 256 + ((((c >> 3) ^ (r & 15)) << 3) | (c & 7));
}
__device__ __forceinline__ int mtidx(int r, int c) {  // mt [128][128]
  return r * 128 + ((((c >> 3) ^ (r & 15)) << 3) | (c & 7));
}

// ---------------- setup kernel 1: build + weight cvt + flag zero ----------------
__global__ __launch_bounds__(256) void k_setup1(
    const int* __restrict__ scene,
    const float* __restrict__ aein, const float* __restrict__ aeout,
    const float* __restrict__ aeid,
    const float* __restrict__ cein, const float* __restrict__ ceout,
    const float* __restrict__ ceid,
    const float* __restrict__ aw1, const float* __restrict__ aw2,
    const float* __restrict__ mw1, const float* __restrict__ mw2,
    unsigned short* __restrict__ dendron_bf, float* __restrict__ axon,
    float* __restrict__ identity,
    unsigned short* __restrict__ w1_bf, unsigned short* __restrict__ w2_bf,
    float* __restrict__ mw1T, float* __restrict__ mw2T,
    unsigned* __restrict__ flags) {
  int blk = blockIdx.x;
  int tid = threadIdx.x;
  if (blk < 4352) {
    int gid = blk * 2 + (tid >> 7);
    int e = tid & 127;
    int b = gid / C, j = gid % C;
    float din, dout, did = 0.f;
    if (j < MC) {
      din  = cein[j * E + e];
      dout = ceout[j * E + e];
      if (e < IDD) did = ceid[j * IDD + e];
    } else {
      int obj = j - MC;
      float sIn = 0.f, sOut = 0.f, sId = 0.f;
      for (int a = 0; a < NATTR; a++) {
        int s = scene[(b * NOBJ + obj) * NATTR + a];
        float m = (s != -1) ? 1.f : 0.f;
        int idx = s + 1;
        sIn  += aein[idx * E + e] * m;
        sOut += aeout[idx * E + e] * m;
        if (e < IDD) sId += aeid[idx * IDD + e] * m;
      }
      din = sIn; dout = sOut; did = sId;
    }
    dendron_bf[(size_t)gid * E + e] = f2b(din);
    axon[(size_t)gid * E + e] = dout;
    if (e < IDD) identity[(size_t)gid * IDD + e] = did;
  } else if (blk < 4544) {
    int i = (blk - 4352) * 256 + tid;
    if (i < HD * E)  w1_bf[i] = f2b(aw1[i]);
    if (i < AD * HD) w2_bf[i] = f2b(aw2[i]);
    if (i < 192 * HD) { int c = i / HD, k = i % HD; mw1T[c * HD + k] = mw1[k * 192 + c]; }
    if (i < HD * AD)  { int k = i / AD, a = i % AD; mw2T[k * AD + a] = mw2[a * HD + k]; }
  } else {
    for (int i = tid; i < 512; i += 256) flags[i] = 0u;
  }
}

// ---------------- setup kernel 2: transA/init + meta + proj ----------------
__global__ __launch_bounds__(256) void k_setup2(
    const float* __restrict__ axon, const float* __restrict__ identity,
    const float* __restrict__ att_init,
    const int* __restrict__ prog_op, const int* __restrict__ prog_arg,
    const float* __restrict__ ceout,
    const float* __restrict__ mw1T, const float* __restrict__ mb1,
    const float* __restrict__ mw2T, const float* __restrict__ mb2,
    unsigned short* __restrict__ axonT, unsigned short* __restrict__ idT_g,
    unsigned short* __restrict__ siaT, float* __restrict__ att_g,
    float* __restrict__ meta_all, float* __restrict__ proj_all) {
  int blk = blockIdx.x;
  int tid = threadIdx.x;
  if (blk < 272) {
    int b = blk / 34, jc = blk % 34;
    int j0 = jc * 64;
    __shared__ float ax[64][129];
    __shared__ float idb[64][65];
    int lane = tid & 63, lr = lane & 15;
    float s = att_init[lane];
    s += __shfl_xor(s, 1, 64);  s += __shfl_xor(s, 2, 64);
    s += __shfl_xor(s, 4, 64);  s += __shfl_xor(s, 8, 64);
    s += __shfl_xor(s, 16, 64); s += __shfl_xor(s, 32, 64);
    float am0 = s * (1.f / AD);
    for (int i = tid; i < 64 * 128; i += 256) {
      int j = i >> 7, e = i & 127;
      ax[j][e] = axon[(size_t)(b * C + j0 + j) * E + e];
    }
    for (int i = tid; i < 64 * 64; i += 256) {
      int j = i >> 6, d = i & 63;
      idb[j][d] = identity[(size_t)(b * C + j0 + j) * IDD + d];
    }
    __syncthreads();
    for (int i = tid; i < 128 * 64; i += 256) {
      int e = i >> 6, jj = i & 63;
      axonT[(size_t)(b * E + e) * C + j0 + jj] = f2b(ax[jj][e]);
    }
    for (int i = tid; i < 64 * 64; i += 256) {
      int d = i >> 6, jj = i & 63;
      idT_g[(size_t)(b * 64 + d) * C + j0 + jj] = f2b(idb[jj][d]);
      siaT[(size_t)(b * 128 + d) * C + j0 + jj] = f2b(idb[jj][d] * am0);
      siaT[(size_t)(b * 128 + 64 + d) * C + j0 + jj] = f2b(att_init[d] * am0);
    }
    {
      float* ag = att_g + (size_t)blk * 4096 + tid * 16;
      #pragma unroll
      for (int n = 0; n < 4; n++) {
        float v0 = att_init[n * 16 + lr];
        #pragma unroll
        for (int v = 0; v < 4; v++) ag[n * 4 + v] = v0;
      }
    }
  } else if (blk < 280) {
    int b = blk - 272;
    __shared__ float x[192];
    __shared__ float h[HD];
    __shared__ float meta[AD];
    if (tid < AD) meta[tid] = att_init[tid];
    __syncthreads();
    for (int t = 0; t < T; t++) {
      int arg = prog_arg[b * T + t];
      if (tid < AD) x[tid] = meta[tid];
      else if (tid < 192) x[tid] = ceout[arg * E + (tid - 64)];
      __syncthreads();
      float s = mb1[tid];
      for (int c = 0; c < 192; c++) s += x[c] * mw1T[c * HD + tid];
      h[tid] = fmaxf(s, 0.f);
      __syncthreads();
      if (tid < AD) {
        float o = mb2[tid];
        for (int k = 0; k < HD; k++) o += h[k] * mw2T[k * AD + tid];
        float m = (prog_op[b * T + t] == 0) ? 1.f : 0.f;
        float nm = m * o + (1.f - m) * meta[tid];
        meta[tid] = nm;
        meta_all[(t * B + b) * AD + tid] = nm;
      }
      __syncthreads();
    }
  } else {
    int gid = (blk - 280) * 4 + (tid >> 6);
    int lane = tid & 63;
    int b = gid / C, i = gid % C;
    float a0 = axon[(size_t)gid * E + lane];
    float a1 = axon[(size_t)gid * E + 64 + lane];
    for (int t = 0; t < T; t++) {
      int arg = prog_arg[b * T + t];
      float p = a0 * ceout[arg * E + lane] + a1 * ceout[arg * E + 64 + lane];
      for (int off = 1; off < 64; off <<= 1) p += __shfl_xor(p, off, 64);
      if (lane == 0) proj_all[(size_t)(t * B + b) * C + i] = p * (1.f / E);
    }
  }
}

// ---------------- two steps per launch ----------------
// Redundant direct-from-global M GEMM (no staging, no sync). Mid-step siaT
// handoff: coherent stores + per-batch flags; odd-step reads PLAIN (fresh
// buffer this launch -> L2 miss -> MALL -> correct, then L2-cached).
__global__ __launch_bounds__(256, 2) void k_step2(
    int t0, int klaunch,
    const unsigned short* __restrict__ dendron_bf,
    const unsigned short* __restrict__ axonT,
    const unsigned short* __restrict__ idT_g,
    const unsigned short* __restrict__ s_in,
    unsigned short* __restrict__ s_mid,
    unsigned short* __restrict__ s_out,
    const unsigned short* __restrict__ w1_bf, const float* __restrict__ b1g,
    const unsigned short* __restrict__ w2_bf, const float* __restrict__ b2g,
    const float* __restrict__ proj_all, const float* __restrict__ meta_all,
    const int* __restrict__ prog_op,
    float* __restrict__ att_g, float* __restrict__ rowmean,
    float* __restrict__ att_hist, float* __restrict__ ins_hist,
    float* __restrict__ trans_hist,
    unsigned* __restrict__ cflag) {
  const int blk = blockIdx.x;
  const int b = blk / 34, ch = blk % 34, j0 = ch * 64;
  const int tid = threadIdx.x;
  const int w = tid >> 6, lane = tid & 63, lr = lane & 15, lg = lane >> 4;

  __shared__ unsigned short smem[24576];        // 48 KB overlay
  __shared__ float am_l[64];
  unsigned short* g_l = smem;                   // [0,16K)
  unsigned short* mt  = smem + 8192;            // [16K,48K)
  unsigned short* h_l = smem + 8192;

  const f32x4 z = {0.f, 0.f, 0.f, 0.f};

  // attention state (persists across both sub-steps in registers)
  float att[4][4];
  {
    const f32x4* ag = (const f32x4*)(att_g + (size_t)blk * 4096 + tid * 16);
    #pragma unroll
    for (int n = 0; n < 4; n++) {
      f32x4 v4 = ag[n];
      #pragma unroll
      for (int v = 0; v < 4; v++) att[n][v] = v4[v];
    }
  }
  // step-invariant dendron A-fragments
  s16x8 afr[4];
  #pragma unroll
  for (int ke = 0; ke < 4; ke++)
    afr[ke] = *(const s16x8*)(dendron_bf + (size_t)(b * C + j0 + w * 16 + lr) * E + ke * 32 + lg * 8);

  for (int sub = 0; sub < 2; sub++) {
    const int t = t0 + sub;
    const unsigned short* sia_src = sub ? s_mid : s_in;
    if (sub == 1) {
      // gate: all 34 blocks of this batch have published s_mid
      if (tid < 34) {
        while (ld_coh_u32(cflag + b * 34 + tid) < (unsigned)(klaunch + 1))
          __builtin_amdgcn_s_sleep(2);
      }
      __syncthreads();
    }
    // ---- redundant GEMM: M[128][128] = sia_src[b] @ axonT[b]^T, direct global ----
    f32x4 acc[2][8];
    #pragma unroll
    for (int dt = 0; dt < 2; dt++)
      #pragma unroll
      for (int n = 0; n < 8; n++) acc[dt][n] = z;
    {
      const unsigned short* ap0 = sia_src + (size_t)(b * 128 + w * 32 + lr) * C + lg * 8;
      const unsigned short* ap1 = ap0 + (size_t)16 * C;
      const unsigned short* bp0 = axonT + (size_t)(b * E + lr) * C + lg * 8;
      #pragma unroll 2
      for (int kk = 0; kk < 68; kk++) {
        int k0 = kk * 32;
        s16x8 A0 = *(const s16x8*)(ap0 + k0);
        s16x8 A1 = *(const s16x8*)(ap1 + k0);
        #pragma unroll
        for (int n = 0; n < 8; n++) {
          s16x8 Bn = *(const s16x8*)(bp0 + (size_t)n * 16 * C + k0);
          acc[0][n] = __builtin_amdgcn_mfma_f32_16x16x32_bf16(A0, Bn, acc[0][n], 0, 0, 0);
          acc[1][n] = __builtin_amdgcn_mfma_f32_16x16x32_bf16(A1, Bn, acc[1][n], 0, 0, 0);
        }
      }
    }
    if (sub == 0) __syncthreads();   // (harmless; uniform structure)
    // acc -> mt (bf16, swizzled): row d = w*32+dt*16+lg*4+v, col e = n*16+lr
    #pragma unroll
    for (int dt = 0; dt < 2; dt++)
      #pragma unroll
      for (int n = 0; n < 8; n++)
        #pragma unroll
        for (int v = 0; v < 4; v++)
          mt[mtidx(w * 32 + dt * 16 + lg * 4 + v, n * 16 + lr)] = f2b(acc[dt][n][v]);
    __syncthreads();
    // ---- phase A: g = dendron @ M / C ----
    {
      #pragma unroll
      for (int n = 0; n < 8; n++) {
        f32x4 a2 = z;
        #pragma unroll
        for (int ke = 0; ke < 4; ke++) {
          s16x8 bf = *(const s16x8*)&mt[mtidx(n * 16 + lr, ke * 32 + lg * 8)];
          a2 = __builtin_amdgcn_mfma_f32_16x16x32_bf16(afr[ke], bf, a2, 0, 0, 0);
        }
        #pragma unroll
        for (int v = 0; v < 4; v++)
          g_l[gidx(w * 16 + lg * 4 + v, n * 16 + lr)] = f2b(a2[v] * (1.f / C));
      }
    }
    __syncthreads();
    // ---- phase B: h = relu(g @ w1^T + b1)  (h overlays mt) ----
    {
      s16x8 gf[4];
      #pragma unroll
      for (int kd = 0; kd < 4; kd++)
        gf[kd] = *(const s16x8*)&g_l[gidx(w * 16 + lr, kd * 32 + lg * 8)];
      #pragma unroll
      for (int n = 0; n < 16; n++) {
        f32x4 a2 = z;
        #pragma unroll
        for (int kd = 0; kd < 4; kd++) {
          s16x8 bf = *(const s16x8*)(w1_bf + (size_t)(n * 16 + lr) * E + kd * 32 + lg * 8);
          a2 = __builtin_amdgcn_mfma_f32_16x16x32_bf16(gf[kd], bf, a2, 0, 0, 0);
        }
        float b1v = b1g[n * 16 + lr];
        #pragma unroll
        for (int v = 0; v < 4; v++)
          h_l[hidx(w * 16 + lg * 4 + v, n * 16 + lr)] = f2b(fmaxf(a2[v] + b1v, 0.f));
      }
    }
    __syncthreads();
    // ---- phase C: out = h @ w2^T ; update att ; hist ----
    {
      s16x8 hf[8];
      #pragma unroll
      for (int kk = 0; kk < 8; kk++)
        hf[kk] = *(const s16x8*)&h_l[hidx(w * 16 + lr, kk * 32 + lg * 8)];
      int op = prog_op[b * T + t];
      float insF = (op == 1) ? 1.f : 0.f, trF = (op == 2) ? 1.f : 0.f;
      float projv[4];
      #pragma unroll
      for (int v = 0; v < 4; v++)
        projv[v] = proj_all[(size_t)(t * B + b) * C + j0 + w * 16 + lg * 4 + v];
      #pragma unroll
      for (int n = 0; n < 4; n++) {
        f32x4 a2 = z;
        #pragma unroll
        for (int kk = 0; kk < 8; kk++) {
          s16x8 bf = *(const s16x8*)(w2_bf + (size_t)(n * 16 + lr) * HD + kk * 32 + lg * 8);
          a2 = __builtin_amdgcn_mfma_f32_16x16x32_bf16(hf[kk], bf, a2, 0, 0, 0);
        }
        int a = n * 16 + lr;
        float b2v = b2g[a];
        float meta_a = meta_all[(size_t)(t * B + b) * AD + a];
        #pragma unroll
        for (int v = 0; v < 4; v++) {
          int row = lg * 4 + v;
          int i = j0 + w * 16 + row;
          float transfer = a2[v] + b2v + b2f(g_l[gidx(w * 16 + row, 64 + a)]);
          float insert = meta_a * projv[v];
          float attv = att[n][v] + insF * insert + trF * transfer;
          attv = (attv >= 0.f) ? attv : 0.01f * attv;
          attv = fminf(fmaxf(attv, -1.f), 2.f);
          att[n][v] = attv;
          size_t hi = (((size_t)t * B + b) * C + i) * AD + a;
          __builtin_nontemporal_store(attv, att_hist + hi);
          __builtin_nontemporal_store(insert, ins_hist + hi);
          __builtin_nontemporal_store(transfer, trans_hist + hi);
        }
      }
    }
    // ---- epilogue: amean ----
    float amr[4];
    {
      float s[4];
      #pragma unroll
      for (int v = 0; v < 4; v++) s[v] = att[0][v] + att[1][v] + att[2][v] + att[3][v];
      #pragma unroll
      for (int v = 0; v < 4; v++) {
        s[v] += __shfl_xor(s[v], 1, 64);
        s[v] += __shfl_xor(s[v], 2, 64);
        s[v] += __shfl_xor(s[v], 4, 64);
        s[v] += __shfl_xor(s[v], 8, 64);
        amr[v] = s[v] * (1.f / AD);
      }
      if (lr == 0) {
        #pragma unroll
        for (int v = 0; v < 4; v++) am_l[w * 16 + lg * 4 + v] = amr[v];
      }
    }
    if (sub == 0) {
      // publish s_mid (coherent) + flag
      #pragma unroll
      for (int n = 0; n < 4; n++) {
        unsigned long long pk = 0;
        #pragma unroll
        for (int v = 0; v < 4; v++)
          pk |= (unsigned long long)f2b(att[n][v] * amr[v]) << (16 * v);
        st_coh_u64((unsigned long long*)(s_mid + (size_t)(b * 128 + 64 + n * 16 + lr) * C + j0 + w * 16 + lg * 4), pk);
      }
      __syncthreads();   // am_l ready
      #pragma unroll
      for (int k2 = 0; k2 < 2; k2++) {
        int idx = tid + k2 * 256;
        int d = idx >> 3, part = idx & 7;
        int j = part * 8;
        s16x8 iv = *(const s16x8*)(idT_g + (size_t)(b * 64 + d) * C + j0 + j);
        union { s16x8 v; unsigned long long u[2]; } ov;
        #pragma unroll
        for (int m = 0; m < 8; m++)
          ov.v[m] = (short)f2b(b2f((unsigned short)iv[m]) * am_l[j + m]);
        unsigned long long* dst = (unsigned long long*)(s_mid + (size_t)(b * 128 + d) * C + j0 + j);
        st_coh_u64(dst, ov.u[0]);
        st_coh_u64(dst + 1, ov.u[1]);
      }
      asm volatile("s_waitcnt vmcnt(0)" ::: "memory");
      __syncthreads();
      if (tid == 0) st_coh_u32(cflag + b * 34 + ch, (unsigned)(klaunch + 1));
    } else if (t < T - 1) {
      // publish s_out (plain — next launch reads it via boundary coherence)
      #pragma unroll
      for (int n = 0; n < 4; n++) {
        unsigned long long pk = 0;
        #pragma unroll
        for (int v = 0; v < 4; v++)
          pk |= (unsigned long long)f2b(att[n][v] * amr[v]) << (16 * v);
        *(unsigned long long*)(s_out + (size_t)(b * 128 + 64 + n * 16 + lr) * C + j0 + w * 16 + lg * 4) = pk;
      }
      __syncthreads();   // am_l ready
      #pragma unroll
      for (int k2 = 0; k2 < 2; k2++) {
        int idx = tid + k2 * 256;
        int d = idx >> 3, part = idx & 7;
        int j = part * 8;
        s16x8 iv = *(const s16x8*)(idT_g + (size_t)(b * 64 + d) * C + j0 + j);
        s16x8 ov;
        #pragma unroll
        for (int m = 0; m < 8; m++)
          ov[m] = (short)f2b(b2f((unsigned short)iv[m]) * am_l[j + m]);
        *(s16x8*)(s_out + (size_t)(b * 128 + d) * C + j0 + j) = ov;
      }
    } else {
      if (lr == 0) {
        #pragma unroll
        for (int v = 0; v < 4; v++)
          rowmean[(size_t)b * C + j0 + w * 16 + lg * 4 + v] = amr[v];
      }
    }
  }
  // persist attention state for next launch
  {
    f32x4* ag = (f32x4*)(att_g + (size_t)blk * 4096 + tid * 16);
    #pragma unroll
    for (int n = 0; n < 4; n++) {
      f32x4 v4;
      #pragma unroll
      for (int v = 0; v < 4; v++) v4[v] = att[n][v];
      ag[n] = v4;
    }
  }
}

// ---------------- final softmax ----------------
__global__ void k_softmax(const float* __restrict__ rowmean, float* __restrict__ out) {
  int b = blockIdx.x;
  __shared__ float am[C];
  __shared__ float red[256];
  int tid = threadIdx.x;
  for (int i = tid; i < C; i += 256) am[i] = rowmean[(size_t)b * C + i];
  __syncthreads();
  float mx = -1e30f;
  for (int i = tid; i < C; i += 256) mx = fmaxf(mx, am[i]);
  red[tid] = mx; __syncthreads();
  for (int s = 128; s > 0; s >>= 1) { if (tid < s) red[tid] = fmaxf(red[tid], red[tid + s]); __syncthreads(); }
  mx = red[0]; __syncthreads();
  float sm = 0.f;
  for (int i = tid; i < C; i += 256) sm += expf(am[i] - mx);
  red[tid] = sm; __syncthreads();
  for (int s = 128; s > 0; s >>= 1) { if (tid < s) red[tid] += red[tid + s]; __syncthreads(); }
  float lse = logf(red[0]) + mx;
  for (int i = tid; i < C; i += 256) out[(size_t)b * C + i] = am[i] - lse;
}

extern "C" void kernel_launch(void* const* d_in, const int* in_sizes, int n_in,
                              void* d_out, int out_size, void* d_ws, size_t ws_size,
                              hipStream_t stream) {
  const int* scene     = (const int*)d_in[0];
  const int* prog_op   = (const int*)d_in[1];
  const int* prog_arg  = (const int*)d_in[2];
  const float* aein    = (const float*)d_in[3];
  const float* aeout   = (const float*)d_in[4];
  const float* aeid    = (const float*)d_in[5];
  const float* cein    = (const float*)d_in[6];
  const float* ceout   = (const float*)d_in[7];
  const float* ceid    = (const float*)d_in[8];
  const float* att_init = (const float*)d_in[11];
  const float* aw1 = (const float*)d_in[12];
  const float* ab1 = (const float*)d_in[13];
  const float* aw2 = (const float*)d_in[14];
  const float* ab2 = (const float*)d_in[15];
  const float* mw1 = (const float*)d_in[16];
  const float* mb1 = (const float*)d_in[17];
  const float* mw2 = (const float*)d_in[18];
  const float* mb2 = (const float*)d_in[19];

  char* ws = (char*)d_ws;
  size_t off = 0;
  auto carve = [&](size_t bytes) { char* p = ws + off; off += (bytes + 255) & ~(size_t)255; return p; };
  float* axon      = (float*)carve((size_t)B * C * E * 4);
  float* identity  = (float*)carve((size_t)B * C * IDD * 4);
  float* proj_all  = (float*)carve((size_t)T * B * C * 4);
  float* meta_all  = (float*)carve((size_t)T * B * AD * 4);
  float* mw1T      = (float*)carve((size_t)192 * HD * 4);
  float* mw2T      = (float*)carve((size_t)HD * AD * 4);
  float* rowmean   = (float*)carve((size_t)B * C * 4);
  float* att_g     = (float*)carve((size_t)272 * 4096 * 4);
  unsigned short* dendron_bf = (unsigned short*)carve((size_t)B * C * E * 2);
  unsigned short* axonT      = (unsigned short*)carve((size_t)B * E * C * 2);
  unsigned short* idT_g      = (unsigned short*)carve((size_t)B * 64 * C * 2);
  unsigned short* siaT0      = (unsigned short*)carve((size_t)B * 128 * C * 2);
  unsigned short* siaT1      = (unsigned short*)carve((size_t)B * 128 * C * 2);
  unsigned short* siaMid     = (unsigned short*)carve((size_t)B * 128 * C * 2);
  unsigned short* w1_bf      = (unsigned short*)carve((size_t)HD * E * 2);
  unsigned short* w2_bf      = (unsigned short*)carve((size_t)AD * HD * 2);
  unsigned*       cflag      = (unsigned*)carve(2048);   // [8][34]

  float* out_sm     = (float*)d_out;
  float* att_hist   = out_sm + B * C;
  float* ins_hist   = att_hist + (size_t)T * B * C * AD;
  float* trans_hist = ins_hist + (size_t)T * B * C * AD;

  k_setup1<<<dim3(4545), dim3(256), 0, stream>>>(scene, aein, aeout, aeid, cein, ceout, ceid,
                                                 aw1, aw2, mw1, mw2,
                                                 dendron_bf, axon, identity,
                                                 w1_bf, w2_bf, mw1T, mw2T, cflag);
  k_setup2<<<dim3(1368), dim3(256), 0, stream>>>(axon, identity, att_init,
                                                 prog_op, prog_arg, ceout,
                                                 mw1T, mb1, mw2T, mb2,
                                                 axonT, idT_g, siaT0, att_g,
                                                 meta_all, proj_all);
  for (int k = 0; k < 6; k++) {
    const unsigned short* sin = (k & 1) ? siaT1 : siaT0;
    unsigned short* sout      = (k & 1) ? siaT0 : siaT1;
    k_step2<<<dim3(272), dim3(256), 0, stream>>>(2 * k, k, dendron_bf, axonT, idT_g,
                                                 sin, siaMid, sout,
                                                 w1_bf, ab1, w2_bf, ab2,
                                                 proj_all, meta_all, prog_op,
                                                 att_g, rowmean,
                                                 att_hist, ins_hist, trans_hist, cflag);
  }
  k_softmax<<<dim3(B), dim3(256), 0, stream>>>(rowmean, out_sm);
}

// Round 11
// 1248.255 us; speedup vs baseline: 2.4876x; 2.4876x over previous
//
#include <hip/hip_runtime.h>

#define B 8
#define NOBJ 128
#define NATTR 4
#define T 12
#define MC 2048
#define E 128
#define IDD 64
#define AD 64
#define HD 256
#define C 2176

typedef short s16x8 __attribute__((ext_vector_type(8)));
typedef float f32x4 __attribute__((ext_vector_type(4)));

__device__ inline unsigned short f2b(float f) {
  union { float f; unsigned u; } v; v.f = f;
  unsigned r = v.u + 0x7FFFu + ((v.u >> 16) & 1u);
  return (unsigned short)(r >> 16);
}
__device__ inline float b2f(unsigned short u) {
  union { unsigned u; float f; } v; v.u = ((unsigned)u) << 16;
  return v.f;
}

// coherent (MALL-routed) accessors: used for WRITES + flags only.
// Reads of freshly-written buffers are PLAIN (safe: L2 invalidated at launch
// boundary + each buffer plain-read at most once per launch after its
// coherent write -> first touch misses to MALL).  [validated by R10 passing]
__device__ __forceinline__ void st_coh_u64(unsigned long long* p, unsigned long long v) {
  __hip_atomic_store(p, v, __ATOMIC_RELAXED, __HIP_MEMORY_SCOPE_AGENT);
}
__device__ __forceinline__ void st_coh_u32(unsigned* p, unsigned v) {
  __hip_atomic_store(p, v, __ATOMIC_RELAXED, __HIP_MEMORY_SCOPE_AGENT);
}
__device__ __forceinline__ unsigned ld_coh_u32(const unsigned* p) {
  return __hip_atomic_load(p, __ATOMIC_RELAXED, __HIP_MEMORY_SCOPE_AGENT);
}

// LDS swizzles: XOR row bits into the 16B-slot index (conflict-free b128 access)
__device__ __forceinline__ int gidx(int r, int c) {   // g [64][128]
  return r * 128 + ((((c >> 3) ^ (r & 15)) << 3) | (c & 7));
}
__device__ __forceinline__ int hidx(int r, int c) {   // h [64][256]
  return r * 256 + ((((c >> 3) ^ (r & 15)) << 3) | (c & 7));
}
__device__ __forceinline__ int mtidx(int r, int c) {  // mt [128][128]
  return r * 128 + ((((c >> 3) ^ (r & 15)) << 3) | (c & 7));
}

// ---------------- setup kernel 1: build + weight cvt + flag zero ----------------
__global__ __launch_bounds__(256) void k_setup1(
    const int* __restrict__ scene,
    const float* __restrict__ aein, const float* __restrict__ aeout,
    const float* __restrict__ aeid,
    const float* __restrict__ cein, const float* __restrict__ ceout,
    const float* __restrict__ ceid,
    const float* __restrict__ aw1, const float* __restrict__ aw2,
    const float* __restrict__ mw1, const float* __restrict__ mw2,
    unsigned short* __restrict__ dendron_bf, float* __restrict__ axon,
    float* __restrict__ identity,
    unsigned short* __restrict__ w1_bf, unsigned short* __restrict__ w2_bf,
    float* __restrict__ mw1T, float* __restrict__ mw2T,
    unsigned* __restrict__ flags) {
  int blk = blockIdx.x;
  int tid = threadIdx.x;
  if (blk < 4352) {
    int gid = blk * 2 + (tid >> 7);
    int e = tid & 127;
    int b = gid / C, j = gid % C;
    float din, dout, did = 0.f;
    if (j < MC) {
      din  = cein[j * E + e];
      dout = ceout[j * E + e];
      if (e < IDD) did = ceid[j * IDD + e];
    } else {
      int obj = j - MC;
      float sIn = 0.f, sOut = 0.f, sId = 0.f;
      for (int a = 0; a < NATTR; a++) {
        int s = scene[(b * NOBJ + obj) * NATTR + a];
        float m = (s != -1) ? 1.f : 0.f;
        int idx = s + 1;
        sIn  += aein[idx * E + e] * m;
        sOut += aeout[idx * E + e] * m;
        if (e < IDD) sId += aeid[idx * IDD + e] * m;
      }
      din = sIn; dout = sOut; did = sId;
    }
    dendron_bf[(size_t)gid * E + e] = f2b(din);
    axon[(size_t)gid * E + e] = dout;
    if (e < IDD) identity[(size_t)gid * IDD + e] = did;
  } else if (blk < 4544) {
    int i = (blk - 4352) * 256 + tid;
    if (i < HD * E)  w1_bf[i] = f2b(aw1[i]);
    if (i < AD * HD) w2_bf[i] = f2b(aw2[i]);
    if (i < 192 * HD) { int c = i / HD, k = i % HD; mw1T[c * HD + k] = mw1[k * 192 + c]; }
    if (i < HD * AD)  { int k = i / AD, a = i % AD; mw2T[k * AD + a] = mw2[a * HD + k]; }
  } else {
    for (int i = tid; i < 512; i += 256) flags[i] = 0u;
  }
}

// ---------------- setup kernel 2: transA/init + meta + proj ----------------
__global__ __launch_bounds__(256) void k_setup2(
    const float* __restrict__ axon, const float* __restrict__ identity,
    const float* __restrict__ att_init,
    const int* __restrict__ prog_op, const int* __restrict__ prog_arg,
    const float* __restrict__ ceout,
    const float* __restrict__ mw1T, const float* __restrict__ mb1,
    const float* __restrict__ mw2T, const float* __restrict__ mb2,
    unsigned short* __restrict__ axonT, unsigned short* __restrict__ idT_g,
    unsigned short* __restrict__ siaT, float* __restrict__ att_g,
    float* __restrict__ meta_all, float* __restrict__ proj_all) {
  int blk = blockIdx.x;
  int tid = threadIdx.x;
  if (blk < 272) {
    int b = blk / 34, jc = blk % 34;
    int j0 = jc * 64;
    __shared__ float ax[64][129];
    __shared__ float idb[64][65];
    int lane = tid & 63, lr = lane & 15;
    float s = att_init[lane];
    s += __shfl_xor(s, 1, 64);  s += __shfl_xor(s, 2, 64);
    s += __shfl_xor(s, 4, 64);  s += __shfl_xor(s, 8, 64);
    s += __shfl_xor(s, 16, 64); s += __shfl_xor(s, 32, 64);
    float am0 = s * (1.f / AD);
    for (int i = tid; i < 64 * 128; i += 256) {
      int j = i >> 7, e = i & 127;
      ax[j][e] = axon[(size_t)(b * C + j0 + j) * E + e];
    }
    for (int i = tid; i < 64 * 64; i += 256) {
      int j = i >> 6, d = i & 63;
      idb[j][d] = identity[(size_t)(b * C + j0 + j) * IDD + d];
    }
    __syncthreads();
    for (int i = tid; i < 128 * 64; i += 256) {
      int e = i >> 6, jj = i & 63;
      axonT[(size_t)(b * E + e) * C + j0 + jj] = f2b(ax[jj][e]);
    }
    for (int i = tid; i < 64 * 64; i += 256) {
      int d = i >> 6, jj = i & 63;
      idT_g[(size_t)(b * 64 + d) * C + j0 + jj] = f2b(idb[jj][d]);
      siaT[(size_t)(b * 128 + d) * C + j0 + jj] = f2b(idb[jj][d] * am0);
      siaT[(size_t)(b * 128 + 64 + d) * C + j0 + jj] = f2b(att_init[d] * am0);
    }
    {
      float* ag = att_g + (size_t)blk * 4096 + tid * 16;
      #pragma unroll
      for (int n = 0; n < 4; n++) {
        float v0 = att_init[n * 16 + lr];
        #pragma unroll
        for (int v = 0; v < 4; v++) ag[n * 4 + v] = v0;
      }
    }
  } else if (blk < 280) {
    int b = blk - 272;
    __shared__ float x[192];
    __shared__ float h[HD];
    __shared__ float meta[AD];
    if (tid < AD) meta[tid] = att_init[tid];
    __syncthreads();
    for (int t = 0; t < T; t++) {
      int arg = prog_arg[b * T + t];
      if (tid < AD) x[tid] = meta[tid];
      else if (tid < 192) x[tid] = ceout[arg * E + (tid - 64)];
      __syncthreads();
      float s = mb1[tid];
      for (int c = 0; c < 192; c++) s += x[c] * mw1T[c * HD + tid];
      h[tid] = fmaxf(s, 0.f);
      __syncthreads();
      if (tid < AD) {
        float o = mb2[tid];
        for (int k = 0; k < HD; k++) o += h[k] * mw2T[k * AD + tid];
        float m = (prog_op[b * T + t] == 0) ? 1.f : 0.f;
        float nm = m * o + (1.f - m) * meta[tid];
        meta[tid] = nm;
        meta_all[(t * B + b) * AD + tid] = nm;
      }
      __syncthreads();
    }
  } else {
    int gid = (blk - 280) * 4 + (tid >> 6);
    int lane = tid & 63;
    int b = gid / C, i = gid % C;
    float a0 = axon[(size_t)gid * E + lane];
    float a1 = axon[(size_t)gid * E + 64 + lane];
    for (int t = 0; t < T; t++) {
      int arg = prog_arg[b * T + t];
      float p = a0 * ceout[arg * E + lane] + a1 * ceout[arg * E + 64 + lane];
      for (int off = 1; off < 64; off <<= 1) p += __shfl_xor(p, off, 64);
      if (lane == 0) proj_all[(size_t)(t * B + b) * C + i] = p * (1.f / E);
    }
  }
}

// ---------------- 3 steps per launch (R7 machinery, plain cached reads) ----
__global__ __launch_bounds__(256, 2) void k_grp(
    int t0,
    const unsigned short* __restrict__ dendron_bf,
    const unsigned short* __restrict__ axonT,
    const unsigned short* __restrict__ idT_g,
    const unsigned short* __restrict__ sIN,
    unsigned short* __restrict__ sM1,
    unsigned short* __restrict__ sM2,
    unsigned short* __restrict__ sOUT,
    const unsigned short* __restrict__ w1_bf, const float* __restrict__ b1g,
    const unsigned short* __restrict__ w2_bf, const float* __restrict__ b2g,
    const float* __restrict__ proj_all, const float* __restrict__ meta_all,
    const int* __restrict__ prog_op,
    unsigned long long* __restrict__ Mt64,     // 3 sub-buffers of B*4096 u64
    float* __restrict__ att_g, float* __restrict__ rowmean,
    float* __restrict__ att_hist, float* __restrict__ ins_hist,
    float* __restrict__ trans_hist,
    unsigned* __restrict__ mflag, unsigned* __restrict__ cflag) {
  const int blk = blockIdx.x;
  const int b = blk / 34, ch = blk % 34, j0 = ch * 64;
  const int tid = threadIdx.x;
  const int w = tid >> 6, lane = tid & 63, lr = lane & 15, lg = lane >> 4;

  __shared__ unsigned short smem[24576];        // 48 KB overlay
  __shared__ float am_l[64];
  unsigned short* g_l = smem;                   // bytes [0,16K)
  unsigned short* mt  = smem + 8192;            // bytes [16K,48K)
  unsigned short* h_l = smem + 8192;

  const f32x4 z = {0.f, 0.f, 0.f, 0.f};
  const unsigned short* srcs[3] = {sIN, sM1, sM2};
  unsigned short* dsts[3] = {sM1, sM2, sOUT};

  // attention state in registers across the 3 sub-steps
  float att[4][4];
  {
    const f32x4* ag = (const f32x4*)(att_g + (size_t)blk * 4096 + tid * 16);
    #pragma unroll
    for (int n = 0; n < 4; n++) {
      f32x4 v4 = ag[n];
      #pragma unroll
      for (int v = 0; v < 4; v++) att[n][v] = v4[v];
    }
  }
  // step-invariant dendron A-fragments for phase A
  s16x8 afr[4];
  #pragma unroll
  for (int ke = 0; ke < 4; ke++)
    afr[ke] = *(const s16x8*)(dendron_bf + (size_t)(b * C + j0 + w * 16 + lr) * E + ke * 32 + lg * 8);

  for (int sub = 0; sub < 3; sub++) {
    const int t = t0 + sub;
    const unsigned short* sia_src = srcs[sub];
    unsigned long long* MtS = Mt64 + (size_t)sub * (B * 4096);
    // ---- producers: 16 per batch, one 32x32 M-tile each (R7 verbatim) ----
    if (ch < 16) {
      if (sub > 0) {
        if (tid < 34) {
          while (ld_coh_u32(cflag + b * 34 + tid) < (unsigned)t) __builtin_amdgcn_s_sleep(2);
        }
      }
      __syncthreads();
      int d0 = (ch >> 2) * 32, e0 = (ch & 3) * 32;
      const unsigned short* ap0 = sia_src + (size_t)(b * 128 + d0 + lr) * C + w * 544 + lg * 8;
      const unsigned short* ap1 = ap0 + (size_t)16 * C;
      const unsigned short* bp0 = axonT + (size_t)(b * E + e0 + lr) * C + w * 544 + lg * 8;
      const unsigned short* bp1 = bp0 + (size_t)16 * C;
      f32x4 a00 = z, a01 = z, a10 = z, a11 = z;
      #pragma unroll 4
      for (int kk = 0; kk < 17; kk++) {
        int k0 = kk * 32;
        s16x8 A0 = *(const s16x8*)(ap0 + k0);
        s16x8 A1 = *(const s16x8*)(ap1 + k0);
        s16x8 B0 = *(const s16x8*)(bp0 + k0);
        s16x8 B1 = *(const s16x8*)(bp1 + k0);
        a00 = __builtin_amdgcn_mfma_f32_16x16x32_bf16(A0, B0, a00, 0, 0, 0);
        a01 = __builtin_amdgcn_mfma_f32_16x16x32_bf16(A0, B1, a01, 0, 0, 0);
        a10 = __builtin_amdgcn_mfma_f32_16x16x32_bf16(A1, B0, a10, 0, 0, 0);
        a11 = __builtin_amdgcn_mfma_f32_16x16x32_bf16(A1, B1, a11, 0, 0, 0);
      }
      float* mred = (float*)smem;               // [4][32][33]
      #pragma unroll
      for (int v = 0; v < 4; v++) {
        mred[(w * 32 + lg * 4 + v) * 33 + lr]           = a00[v];
        mred[(w * 32 + lg * 4 + v) * 33 + 16 + lr]      = a01[v];
        mred[(w * 32 + 16 + lg * 4 + v) * 33 + lr]      = a10[v];
        mred[(w * 32 + 16 + lg * 4 + v) * 33 + 16 + lr] = a11[v];
      }
      __syncthreads();
      {
        int r = tid >> 3, c = (tid & 7) * 4;
        float s0 = 0.f, s1 = 0.f, s2 = 0.f, s3 = 0.f;
        #pragma unroll
        for (int w4 = 0; w4 < 4; w4++) {
          const float* p = &mred[(w4 * 32 + r) * 33 + c];
          s0 += p[0]; s1 += p[1]; s2 += p[2]; s3 += p[3];
        }
        unsigned long long pk = (unsigned long long)f2b(s0)
                              | ((unsigned long long)f2b(s1) << 16)
                              | ((unsigned long long)f2b(s2) << 32)
                              | ((unsigned long long)f2b(s3) << 48);
        st_coh_u64(MtS + (((size_t)(b * 128 + d0 + r) * 128) + e0 + c) / 4, pk);
      }
      asm volatile("s_waitcnt vmcnt(0)" ::: "memory");
      __syncthreads();
      if (tid == 0) st_coh_u32(mflag + b * 16 + ch, (unsigned)(t + 1));
    }
    // ---- all blocks: wait for this batch's 16 M-tiles ----
    if (tid < 16) {
      while (ld_coh_u32(mflag + b * 16 + tid) < (unsigned)(t + 1)) __builtin_amdgcn_s_sleep(2);
    }
    __syncthreads();
    // ---- stage Mt -> LDS (PLAIN cached loads; fresh via MALL first-touch) ----
    {
      const unsigned long long* mtp = MtS + (size_t)b * 4096;
      #pragma unroll
      for (int k = 0; k < 16; k++) {
        int idx = tid + k * 256;
        unsigned long long v = mtp[idx];
        int r = idx >> 5, c4 = (idx & 31) * 4;
        *(unsigned long long*)&mt[mtidx(r, c4)] = v;
      }
    }
    __syncthreads();
    // ---- phase A: g = dendron @ M / C ----
    {
      #pragma unroll
      for (int n = 0; n < 8; n++) {
        f32x4 a2 = z;
        #pragma unroll
        for (int ke = 0; ke < 4; ke++) {
          s16x8 bf = *(const s16x8*)&mt[mtidx(n * 16 + lr, ke * 32 + lg * 8)];
          a2 = __builtin_amdgcn_mfma_f32_16x16x32_bf16(afr[ke], bf, a2, 0, 0, 0);
        }
        #pragma unroll
        for (int v = 0; v < 4; v++)
          g_l[gidx(w * 16 + lg * 4 + v, n * 16 + lr)] = f2b(a2[v] * (1.f / C));
      }
    }
    __syncthreads();
    // ---- phase B: h = relu(g @ w1^T + b1) ----
    {
      s16x8 gf[4];
      #pragma unroll
      for (int kd = 0; kd < 4; kd++)
        gf[kd] = *(const s16x8*)&g_l[gidx(w * 16 + lr, kd * 32 + lg * 8)];
      #pragma unroll
      for (int n = 0; n < 16; n++) {
        f32x4 a2 = z;
        #pragma unroll
        for (int kd = 0; kd < 4; kd++) {
          s16x8 bf = *(const s16x8*)(w1_bf + (size_t)(n * 16 + lr) * E + kd * 32 + lg * 8);
          a2 = __builtin_amdgcn_mfma_f32_16x16x32_bf16(gf[kd], bf, a2, 0, 0, 0);
        }
        float b1v = b1g[n * 16 + lr];
        #pragma unroll
        for (int v = 0; v < 4; v++)
          h_l[hidx(w * 16 + lg * 4 + v, n * 16 + lr)] = f2b(fmaxf(a2[v] + b1v, 0.f));
      }
    }
    __syncthreads();
    // ---- phase C: out = h @ w2^T ; update att ; hist ----
    {
      s16x8 hf[8];
      #pragma unroll
      for (int kk = 0; kk < 8; kk++)
        hf[kk] = *(const s16x8*)&h_l[hidx(w * 16 + lr, kk * 32 + lg * 8)];
      int op = prog_op[b * T + t];
      float insF = (op == 1) ? 1.f : 0.f, trF = (op == 2) ? 1.f : 0.f;
      float projv[4];
      #pragma unroll
      for (int v = 0; v < 4; v++)
        projv[v] = proj_all[(size_t)(t * B + b) * C + j0 + w * 16 + lg * 4 + v];
      #pragma unroll
      for (int n = 0; n < 4; n++) {
        f32x4 a2 = z;
        #pragma unroll
        for (int kk = 0; kk < 8; kk++) {
          s16x8 bf = *(const s16x8*)(w2_bf + (size_t)(n * 16 + lr) * HD + kk * 32 + lg * 8);
          a2 = __builtin_amdgcn_mfma_f32_16x16x32_bf16(hf[kk], bf, a2, 0, 0, 0);
        }
        int a = n * 16 + lr;
        float b2v = b2g[a];
        float meta_a = meta_all[(size_t)(t * B + b) * AD + a];
        #pragma unroll
        for (int v = 0; v < 4; v++) {
          int row = lg * 4 + v;
          int i = j0 + w * 16 + row;
          float transfer = a2[v] + b2v + b2f(g_l[gidx(w * 16 + row, 64 + a)]);
          float insert = meta_a * projv[v];
          float attv = att[n][v] + insF * insert + trF * transfer;
          attv = (attv >= 0.f) ? attv : 0.01f * attv;
          attv = fminf(fmaxf(attv, -1.f), 2.f);
          att[n][v] = attv;
          size_t hi = (((size_t)t * B + b) * C + i) * AD + a;
          __builtin_nontemporal_store(attv, att_hist + hi);
          __builtin_nontemporal_store(insert, ins_hist + hi);
          __builtin_nontemporal_store(transfer, trans_hist + hi);
        }
      }
    }
    // ---- epilogue: amean; publish next sia (coherent) + cflag ----
    float amr[4];
    {
      float s[4];
      #pragma unroll
      for (int v = 0; v < 4; v++) s[v] = att[0][v] + att[1][v] + att[2][v] + att[3][v];
      #pragma unroll
      for (int v = 0; v < 4; v++) {
        s[v] += __shfl_xor(s[v], 1, 64);
        s[v] += __shfl_xor(s[v], 2, 64);
        s[v] += __shfl_xor(s[v], 4, 64);
        s[v] += __shfl_xor(s[v], 8, 64);
        amr[v] = s[v] * (1.f / AD);
      }
      if (lr == 0) {
        #pragma unroll
        for (int v = 0; v < 4; v++) am_l[w * 16 + lg * 4 + v] = amr[v];
      }
    }
    if (t < T - 1) {
      unsigned short* s_dst = dsts[sub];
      #pragma unroll
      for (int n = 0; n < 4; n++) {
        unsigned long long pk = 0;
        #pragma unroll
        for (int v = 0; v < 4; v++)
          pk |= (unsigned long long)f2b(att[n][v] * amr[v]) << (16 * v);
        st_coh_u64((unsigned long long*)(s_dst + (size_t)(b * 128 + 64 + n * 16 + lr) * C + j0 + w * 16 + lg * 4), pk);
      }
      __syncthreads();   // am_l ready
      #pragma unroll
      for (int k2 = 0; k2 < 2; k2++) {
        int idx = tid + k2 * 256;
        int d = idx >> 3, part = idx & 7;
        int j = part * 8;
        s16x8 iv = *(const s16x8*)(idT_g + (size_t)(b * 64 + d) * C + j0 + j);
        union { s16x8 v; unsigned long long u[2]; } ov;
        #pragma unroll
        for (int m = 0; m < 8; m++)
          ov.v[m] = (short)f2b(b2f((unsigned short)iv[m]) * am_l[j + m]);
        unsigned long long* dst = (unsigned long long*)(s_dst + (size_t)(b * 128 + d) * C + j0 + j);
        st_coh_u64(dst, ov.u[0]);
        st_coh_u64(dst + 1, ov.u[1]);
      }
      if (sub < 2) {
        asm volatile("s_waitcnt vmcnt(0)" ::: "memory");
        __syncthreads();
        if (tid == 0) st_coh_u32(cflag + b * 34 + ch, (unsigned)(t + 1));
      }
      // sub==2: no flag needed — end-of-kernel release + next-launch acquire
    } else {
      if (lr == 0) {
        #pragma unroll
        for (int v = 0; v < 4; v++)
          rowmean[(size_t)b * C + j0 + w * 16 + lg * 4 + v] = amr[v];
      }
    }
  }
  // persist attention state for next launch
  {
    f32x4* ag = (f32x4*)(att_g + (size_t)blk * 4096 + tid * 16);
    #pragma unroll
    for (int n = 0; n < 4; n++) {
      f32x4 v4;
      #pragma unroll
      for (int v = 0; v < 4; v++) v4[v] = att[n][v];
      ag[n] = v4;
    }
  }
}

// ---------------- final softmax ----------------
__global__ void k_softmax(const float* __restrict__ rowmean, float* __restrict__ out) {
  int b = blockIdx.x;
  __shared__ float am[C];
  __shared__ float red[256];
  int tid = threadIdx.x;
  for (int i = tid; i < C; i += 256) am[i] = rowmean[(size_t)b * C + i];
  __syncthreads();
  float mx = -1e30f;
  for (int i = tid; i < C; i += 256) mx = fmaxf(mx, am[i]);
  red[tid] = mx; __syncthreads();
  for (int s = 128; s > 0; s >>= 1) { if (tid < s) red[tid] = fmaxf(red[tid], red[tid + s]); __syncthreads(); }
  mx = red[0]; __syncthreads();
  float sm = 0.f;
  for (int i = tid; i < C; i += 256) sm += expf(am[i] - mx);
  red[tid] = sm; __syncthreads();
  for (int s = 128; s > 0; s >>= 1) { if (tid < s) red[tid] += red[tid + s]; __syncthreads(); }
  float lse = logf(red[0]) + mx;
  for (int i = tid; i < C; i += 256) out[(size_t)b * C + i] = am[i] - lse;
}

extern "C" void kernel_launch(void* const* d_in, const int* in_sizes, int n_in,
                              void* d_out, int out_size, void* d_ws, size_t ws_size,
                              hipStream_t stream) {
  const int* scene     = (const int*)d_in[0];
  const int* prog_op   = (const int*)d_in[1];
  const int* prog_arg  = (const int*)d_in[2];
  const float* aein    = (const float*)d_in[3];
  const float* aeout   = (const float*)d_in[4];
  const float* aeid    = (const float*)d_in[5];
  const float* cein    = (const float*)d_in[6];
  const float* ceout   = (const float*)d_in[7];
  const float* ceid    = (const float*)d_in[8];
  const float* att_init = (const float*)d_in[11];
  const float* aw1 = (const float*)d_in[12];
  const float* ab1 = (const float*)d_in[13];
  const float* aw2 = (const float*)d_in[14];
  const float* ab2 = (const float*)d_in[15];
  const float* mw1 = (const float*)d_in[16];
  const float* mb1 = (const float*)d_in[17];
  const float* mw2 = (const float*)d_in[18];
  const float* mb2 = (const float*)d_in[19];

  char* ws = (char*)d_ws;
  size_t off = 0;
  auto carve = [&](size_t bytes) { char* p = ws + off; off += (bytes + 255) & ~(size_t)255; return p; };
  float* axon      = (float*)carve((size_t)B * C * E * 4);
  float* identity  = (float*)carve((size_t)B * C * IDD * 4);
  float* proj_all  = (float*)carve((size_t)T * B * C * 4);
  float* meta_all  = (float*)carve((size_t)T * B * AD * 4);
  float* mw1T      = (float*)carve((size_t)192 * HD * 4);
  float* mw2T      = (float*)carve((size_t)HD * AD * 4);
  float* rowmean   = (float*)carve((size_t)B * C * 4);
  float* att_g     = (float*)carve((size_t)272 * 4096 * 4);
  unsigned short* dendron_bf = (unsigned short*)carve((size_t)B * C * E * 2);
  unsigned short* axonT      = (unsigned short*)carve((size_t)B * E * C * 2);
  unsigned short* idT_g      = (unsigned short*)carve((size_t)B * 64 * C * 2);
  unsigned short* siaA       = (unsigned short*)carve((size_t)B * 128 * C * 2);
  unsigned short* siaB       = (unsigned short*)carve((size_t)B * 128 * C * 2);
  unsigned short* siaM1      = (unsigned short*)carve((size_t)B * 128 * C * 2);
  unsigned short* siaM2      = (unsigned short*)carve((size_t)B * 128 * C * 2);
  unsigned long long* Mt64   = (unsigned long long*)carve((size_t)3 * B * 4096 * 8);
  unsigned short* w1_bf      = (unsigned short*)carve((size_t)HD * E * 2);
  unsigned short* w2_bf      = (unsigned short*)carve((size_t)AD * HD * 2);
  unsigned*       flags      = (unsigned*)carve(2048);
  unsigned*       mflag = flags;            // [8][16]
  unsigned*       cflag = flags + 128;      // [8][34]

  float* out_sm     = (float*)d_out;
  float* att_hist   = out_sm + B * C;
  float* ins_hist   = att_hist + (size_t)T * B * C * AD;
  float* trans_hist = ins_hist + (size_t)T * B * C * AD;

  k_setup1<<<dim3(4545), dim3(256), 0, stream>>>(scene, aein, aeout, aeid, cein, ceout, ceid,
                                                 aw1, aw2, mw1, mw2,
                                                 dendron_bf, axon, identity,
                                                 w1_bf, w2_bf, mw1T, mw2T, flags);
  k_setup2<<<dim3(1368), dim3(256), 0, stream>>>(axon, identity, att_init,
                                                 prog_op, prog_arg, ceout,
                                                 mw1T, mb1, mw2T, mb2,
                                                 axonT, idT_g, siaA, att_g,
                                                 meta_all, proj_all);
  for (int g = 0; g < 4; g++) {
    const unsigned short* sin = (g & 1) ? siaB : siaA;
    unsigned short* sout      = (g & 1) ? siaA : siaB;
    k_grp<<<dim3(272), dim3(256), 0, stream>>>(3 * g, dendron_bf, axonT, idT_g,
                                               sin, siaM1, siaM2, sout,
                                               w1_bf, ab1, w2_bf, ab2,
                                               proj_all, meta_all, prog_op,
                                               Mt64, att_g, rowmean,
                                               att_hist, ins_hist, trans_hist,
                                               mflag, cflag);
  }
  k_softmax<<<dim3(B), dim3(256), 0, stream>>>(rowmean, out_sm);
}

// Round 12
// 683.815 us; speedup vs baseline: 4.5409x; 1.8254x over previous
//
#include <hip/hip_runtime.h>

#define B 8
#define NOBJ 128
#define NATTR 4
#define T 12
#define MC 2048
#define E 128
#define IDD 64
#define AD 64
#define HD 256
#define C 2176

typedef short s16x8 __attribute__((ext_vector_type(8)));
typedef float f32x4 __attribute__((ext_vector_type(4)));

__device__ inline unsigned short f2b(float f) {
  union { float f; unsigned u; } v; v.f = f;
  unsigned r = v.u + 0x7FFFu + ((v.u >> 16) & 1u);
  return (unsigned short)(r >> 16);
}
__device__ inline float b2f(unsigned short u) {
  union { unsigned u; float f; } v; v.u = ((unsigned)u) << 16;
  return v.f;
}

// coherent (MALL-routed) accessors: WRITES + flags only. Fresh buffers are
// PLAIN-read after flag (L2 invalidated at launch start; first touch misses
// to MALL). [validated R10/R11 passing]
__device__ __forceinline__ void st_coh_u64(unsigned long long* p, unsigned long long v) {
  __hip_atomic_store(p, v, __ATOMIC_RELAXED, __HIP_MEMORY_SCOPE_AGENT);
}
__device__ __forceinline__ void st_coh_u32(unsigned* p, unsigned v) {
  __hip_atomic_store(p, v, __ATOMIC_RELAXED, __HIP_MEMORY_SCOPE_AGENT);
}
__device__ __forceinline__ unsigned ld_coh_u32(const unsigned* p) {
  return __hip_atomic_load(p, __ATOMIC_RELAXED, __HIP_MEMORY_SCOPE_AGENT);
}

// LDS swizzles: XOR row bits into the 16B-slot index (conflict-free b128)
__device__ __forceinline__ int gidx(int r, int c) {   // g [64][128]
  return r * 128 + ((((c >> 3) ^ (r & 15)) << 3) | (c & 7));
}
__device__ __forceinline__ int hidx(int r, int c) {   // h [64][256]
  return r * 256 + ((((c >> 3) ^ (r & 15)) << 3) | (c & 7));
}
__device__ __forceinline__ int mtidx(int r, int c) {  // mt [128][128]
  return r * 128 + ((((c >> 3) ^ (r & 15)) << 3) | (c & 7));
}

// ---------------- single merged setup kernel ----------------
__global__ __launch_bounds__(256) void k_setup(
    const int* __restrict__ scene,
    const float* __restrict__ aein, const float* __restrict__ aeout,
    const float* __restrict__ aeid,
    const float* __restrict__ cein, const float* __restrict__ ceout,
    const float* __restrict__ ceid,
    const float* __restrict__ att_init,
    const int* __restrict__ prog_op, const int* __restrict__ prog_arg,
    const float* __restrict__ aw1, const float* __restrict__ aw2,
    const float* __restrict__ mw1, const float* __restrict__ mb1,
    const float* __restrict__ mw2, const float* __restrict__ mb2,
    unsigned short* __restrict__ dendron_bf,
    unsigned short* __restrict__ w1_bf, unsigned short* __restrict__ w2_bf,
    unsigned short* __restrict__ axonT, unsigned short* __restrict__ idT_g,
    unsigned short* __restrict__ siaT, float* __restrict__ att_g,
    float* __restrict__ meta_all, float* __restrict__ proj_all,
    unsigned* __restrict__ flags) {
  int blk = blockIdx.x;
  int tid = threadIdx.x;
  if (blk < 4352) {
    // ---- dendron_bf build: 2 (b,j) rows per block ----
    int gid = blk * 2 + (tid >> 7);
    int e = tid & 127;
    int b = gid / C, j = gid % C;
    float din;
    if (j < MC) {
      din = cein[j * E + e];
    } else {
      int obj = j - MC;
      float sIn = 0.f;
      for (int a = 0; a < NATTR; a++) {
        int s = scene[(b * NOBJ + obj) * NATTR + a];
        float m = (s != -1) ? 1.f : 0.f;
        sIn += aein[(s + 1) * E + e] * m;
      }
      din = sIn;
    }
    dendron_bf[(size_t)gid * E + e] = f2b(din);
  } else if (blk < 4544) {
    // ---- weight conversions ----
    int i = (blk - 4352) * 256 + tid;
    if (i < HD * E)  w1_bf[i] = f2b(aw1[i]);
    if (i < AD * HD) w2_bf[i] = f2b(aw2[i]);
    float* mw1T = meta_all + (size_t)T * B * AD;          // scratch tail (unused slot safe)
    (void)mw1T;
  } else if (blk < 4816) {
    // ---- transA + idT + siaT(0) + att_g(0), self-gathering ----
    int sb = blk - 4544;
    int b = sb / 34, jc = sb % 34;
    int j0 = jc * 64;
    __shared__ float ax[64][129];
    __shared__ float idb[64][65];
    int lane = tid & 63, lr = lane & 15;
    float s = att_init[lane];
    s += __shfl_xor(s, 1, 64);  s += __shfl_xor(s, 2, 64);
    s += __shfl_xor(s, 4, 64);  s += __shfl_xor(s, 8, 64);
    s += __shfl_xor(s, 16, 64); s += __shfl_xor(s, 32, 64);
    float am0 = s * (1.f / AD);
    for (int i = tid; i < 64 * 128; i += 256) {
      int j = i >> 7, e = i & 127;
      int jg = j0 + j;
      float v;
      if (jg < MC) v = ceout[jg * E + e];
      else {
        int obj = jg - MC;
        v = 0.f;
        for (int a = 0; a < NATTR; a++) {
          int sc = scene[(b * NOBJ + obj) * NATTR + a];
          float m = (sc != -1) ? 1.f : 0.f;
          v += aeout[(sc + 1) * E + e] * m;
        }
      }
      ax[j][e] = v;
    }
    for (int i = tid; i < 64 * 64; i += 256) {
      int j = i >> 6, d = i & 63;
      int jg = j0 + j;
      float v;
      if (jg < MC) v = ceid[jg * IDD + d];
      else {
        int obj = jg - MC;
        v = 0.f;
        for (int a = 0; a < NATTR; a++) {
          int sc = scene[(b * NOBJ + obj) * NATTR + a];
          float m = (sc != -1) ? 1.f : 0.f;
          v += aeid[(sc + 1) * IDD + d] * m;
        }
      }
      idb[j][d] = v;
    }
    __syncthreads();
    for (int i = tid; i < 128 * 64; i += 256) {
      int e = i >> 6, jj = i & 63;
      axonT[(size_t)(b * E + e) * C + j0 + jj] = f2b(ax[jj][e]);
    }
    for (int i = tid; i < 64 * 64; i += 256) {
      int d = i >> 6, jj = i & 63;
      idT_g[(size_t)(b * 64 + d) * C + j0 + jj] = f2b(idb[jj][d]);
      siaT[(size_t)(b * 128 + d) * C + j0 + jj] = f2b(idb[jj][d] * am0);
      siaT[(size_t)(b * 128 + 64 + d) * C + j0 + jj] = f2b(att_init[d] * am0);
    }
    {
      float* ag = att_g + (size_t)sb * 4096 + tid * 16;
      #pragma unroll
      for (int n = 0; n < 4; n++) {
        float v0 = att_init[n * 16 + lr];
        #pragma unroll
        for (int v = 0; v < 4; v++) ag[n * 4 + v] = v0;
      }
    }
  } else if (blk < 4824) {
    // ---- meta scan (coalesced via transposed reads on the fly) ----
    int b = blk - 4816;
    __shared__ float x[192];
    __shared__ float h[HD];
    __shared__ float meta[AD];
    if (tid < AD) meta[tid] = att_init[tid];
    __syncthreads();
    for (int t = 0; t < T; t++) {
      int arg = prog_arg[b * T + t];
      if (tid < AD) x[tid] = meta[tid];
      else if (tid < 192) x[tid] = ceout[arg * E + (tid - 64)];
      __syncthreads();
      float s = mb1[tid];
      for (int c = 0; c < 192; c++) s += x[c] * mw1[tid * 192 + c];
      h[tid] = fmaxf(s, 0.f);
      __syncthreads();
      if (tid < AD) {
        float o = mb2[tid];
        for (int k = 0; k < HD; k++) o += h[k] * mw2[tid * HD + k];
        float m = (prog_op[b * T + t] == 0) ? 1.f : 0.f;
        float nm = m * o + (1.f - m) * meta[tid];
        meta[tid] = nm;
        meta_all[(t * B + b) * AD + tid] = nm;
      }
      __syncthreads();
    }
  } else if (blk < 9176) {
    // ---- proj (self-gathering axon rows) ----
    int gid = (blk - 4824) * 4 + (tid >> 6);
    int lane = tid & 63;
    int b = gid / C, i = gid % C;
    float a0, a1;
    if (i < MC) {
      a0 = ceout[i * E + lane];
      a1 = ceout[i * E + 64 + lane];
    } else {
      int obj = i - MC;
      a0 = 0.f; a1 = 0.f;
      for (int a = 0; a < NATTR; a++) {
        int sc = scene[(b * NOBJ + obj) * NATTR + a];
        float m = (sc != -1) ? 1.f : 0.f;
        a0 += aeout[(sc + 1) * E + lane] * m;
        a1 += aeout[(sc + 1) * E + 64 + lane] * m;
      }
    }
    for (int t = 0; t < T; t++) {
      int arg = prog_arg[b * T + t];
      float p = a0 * ceout[arg * E + lane] + a1 * ceout[arg * E + 64 + lane];
      for (int off2 = 1; off2 < 64; off2 <<= 1) p += __shfl_xor(p, off2, 64);
      if (lane == 0) proj_all[(size_t)(t * B + b) * C + i] = p * (1.f / E);
    }
  } else {
    if (tid < 256) flags[tid] = 0u;
  }
}

// ---------------- fused per-step kernel (R7, Mt staged PLAIN) ----------------
// blocks 34 per batch; ch<16 also produce one 32x32 M-tile first.
__global__ __launch_bounds__(256) void k_step(
    int t,
    const unsigned short* __restrict__ dendron_bf,
    const unsigned short* __restrict__ axonT,
    const unsigned short* __restrict__ idT_g,
    const unsigned short* __restrict__ siaT_in,
    const unsigned short* __restrict__ w1_bf, const float* __restrict__ b1g,
    const unsigned short* __restrict__ w2_bf, const float* __restrict__ b2g,
    const float* __restrict__ proj_all, const float* __restrict__ meta_all,
    const int* __restrict__ prog_op,
    unsigned long long* __restrict__ Mt64,
    float* __restrict__ att_g, unsigned short* __restrict__ siaT_out,
    float* __restrict__ rowmean,
    float* __restrict__ att_hist, float* __restrict__ ins_hist,
    float* __restrict__ trans_hist,
    unsigned* __restrict__ mflag) {
  const int blk = blockIdx.x;
  const int b = blk / 34, ch = blk % 34, j0 = ch * 64;
  const int tid = threadIdx.x;
  const int w = tid >> 6, lane = tid & 63, lr = lane & 15, lg = lane >> 4;

  __shared__ unsigned short smem[24576];           // 48 KB overlay
  __shared__ float am_l[64];
  unsigned short* g_l = smem;                      // bytes [0,16K)
  unsigned short* mt  = smem + 8192;               // bytes [16K,48K)
  unsigned short* h_l = smem + 8192;
  float* mred = (float*)smem;                      // producer scratch [4][32][33]

  const f32x4 z = {0.f, 0.f, 0.f, 0.f};
  const unsigned ph = (unsigned)(t + 1);

  // load attention state early (independent of M)
  float att[4][4];
  {
    const f32x4* ag = (const f32x4*)(att_g + (size_t)blk * 4096 + tid * 16);
    #pragma unroll
    for (int n = 0; n < 4; n++) {
      f32x4 v4 = ag[n];
      #pragma unroll
      for (int v = 0; v < 4; v++) att[n][v] = v4[v];
    }
  }

  // ---- producers: ch<16 compute one 32x32 tile of M = siaT @ axonT^T ----
  if (ch < 16) {
    int d0 = (ch >> 2) * 32, e0 = (ch & 3) * 32;
    const unsigned short* ap0 = siaT_in + (size_t)(b * 128 + d0 + lr) * C + w * 544 + lg * 8;
    const unsigned short* ap1 = ap0 + (size_t)16 * C;
    const unsigned short* bp0 = axonT + (size_t)(b * E + e0 + lr) * C + w * 544 + lg * 8;
    const unsigned short* bp1 = bp0 + (size_t)16 * C;
    f32x4 a00 = z, a01 = z, a10 = z, a11 = z;
    #pragma unroll 4
    for (int kk = 0; kk < 17; kk++) {
      int k0 = kk * 32;
      s16x8 A0 = *(const s16x8*)(ap0 + k0);
      s16x8 A1 = *(const s16x8*)(ap1 + k0);
      s16x8 B0 = *(const s16x8*)(bp0 + k0);
      s16x8 B1 = *(const s16x8*)(bp1 + k0);
      a00 = __builtin_amdgcn_mfma_f32_16x16x32_bf16(A0, B0, a00, 0, 0, 0);
      a01 = __builtin_amdgcn_mfma_f32_16x16x32_bf16(A0, B1, a01, 0, 0, 0);
      a10 = __builtin_amdgcn_mfma_f32_16x16x32_bf16(A1, B0, a10, 0, 0, 0);
      a11 = __builtin_amdgcn_mfma_f32_16x16x32_bf16(A1, B1, a11, 0, 0, 0);
    }
    #pragma unroll
    for (int v = 0; v < 4; v++) {
      mred[(w * 32 + lg * 4 + v) * 33 + lr]           = a00[v];
      mred[(w * 32 + lg * 4 + v) * 33 + 16 + lr]      = a01[v];
      mred[(w * 32 + 16 + lg * 4 + v) * 33 + lr]      = a10[v];
      mred[(w * 32 + 16 + lg * 4 + v) * 33 + 16 + lr] = a11[v];
    }
    __syncthreads();
    {
      int r = tid >> 3, c = (tid & 7) * 4;
      float s0 = 0.f, s1 = 0.f, s2 = 0.f, s3 = 0.f;
      #pragma unroll
      for (int w4 = 0; w4 < 4; w4++) {
        const float* p = &mred[(w4 * 32 + r) * 33 + c];
        s0 += p[0]; s1 += p[1]; s2 += p[2]; s3 += p[3];
      }
      unsigned long long pk = (unsigned long long)f2b(s0)
                            | ((unsigned long long)f2b(s1) << 16)
                            | ((unsigned long long)f2b(s2) << 32)
                            | ((unsigned long long)f2b(s3) << 48);
      st_coh_u64(Mt64 + (((size_t)(b * 128 + d0 + r) * 128) + e0 + c) / 4, pk);
    }
    asm volatile("s_waitcnt vmcnt(0)" ::: "memory");
    __syncthreads();
    if (tid == 0) st_coh_u32(mflag + b * 16 + ch, ph);
  }
  // ---- all blocks: wait for this batch's 16 M-tiles ----
  if (tid < 16) {
    while (ld_coh_u32(mflag + b * 16 + tid) < ph) __builtin_amdgcn_s_sleep(1);
  }
  __syncthreads();
  // ---- stage Mt -> LDS (PLAIN cached loads; first touch misses to MALL) ----
  {
    const unsigned long long* mtp = Mt64 + (size_t)b * 4096;
    #pragma unroll
    for (int k = 0; k < 16; k++) {
      int idx = tid + k * 256;
      unsigned long long v = mtp[idx];
      int r = idx >> 5, c4 = (idx & 31) * 4;
      *(unsigned long long*)&mt[mtidx(r, c4)] = v;
    }
  }
  __syncthreads();
  // ---- phase A: g = dendron @ M / C ----
  {
    s16x8 afr[4];
    #pragma unroll
    for (int ke = 0; ke < 4; ke++)
      afr[ke] = *(const s16x8*)(dendron_bf + (size_t)(b * C + j0 + w * 16 + lr) * E + ke * 32 + lg * 8);
    #pragma unroll
    for (int n = 0; n < 8; n++) {
      f32x4 acc = z;
      #pragma unroll
      for (int ke = 0; ke < 4; ke++) {
        s16x8 bf = *(const s16x8*)&mt[mtidx(n * 16 + lr, ke * 32 + lg * 8)];
        acc = __builtin_amdgcn_mfma_f32_16x16x32_bf16(afr[ke], bf, acc, 0, 0, 0);
      }
      #pragma unroll
      for (int v = 0; v < 4; v++)
        g_l[gidx(w * 16 + lg * 4 + v, n * 16 + lr)] = f2b(acc[v] * (1.f / C));
    }
  }
  __syncthreads();
  // ---- phase B: h = relu(g @ w1^T + b1) ----
  {
    s16x8 gf[4];
    #pragma unroll
    for (int kd = 0; kd < 4; kd++)
      gf[kd] = *(const s16x8*)&g_l[gidx(w * 16 + lr, kd * 32 + lg * 8)];
    #pragma unroll
    for (int n = 0; n < 16; n++) {
      f32x4 acc = z;
      #pragma unroll
      for (int kd = 0; kd < 4; kd++) {
        s16x8 bf = *(const s16x8*)(w1_bf + (size_t)(n * 16 + lr) * E + kd * 32 + lg * 8);
        acc = __builtin_amdgcn_mfma_f32_16x16x32_bf16(gf[kd], bf, acc, 0, 0, 0);
      }
      float b1v = b1g[n * 16 + lr];
      #pragma unroll
      for (int v = 0; v < 4; v++)
        h_l[hidx(w * 16 + lg * 4 + v, n * 16 + lr)] = f2b(fmaxf(acc[v] + b1v, 0.f));
    }
  }
  __syncthreads();
  // ---- phase C: out = h @ w2^T ; update att ; hist ----
  {
    s16x8 hf[8];
    #pragma unroll
    for (int kk = 0; kk < 8; kk++)
      hf[kk] = *(const s16x8*)&h_l[hidx(w * 16 + lr, kk * 32 + lg * 8)];
    int op = prog_op[b * T + t];
    float insF = (op == 1) ? 1.f : 0.f, trF = (op == 2) ? 1.f : 0.f;
    float projv[4];
    #pragma unroll
    for (int v = 0; v < 4; v++)
      projv[v] = proj_all[(size_t)(t * B + b) * C + j0 + w * 16 + lg * 4 + v];
    #pragma unroll
    for (int n = 0; n < 4; n++) {
      f32x4 acc = z;
      #pragma unroll
      for (int kk = 0; kk < 8; kk++) {
        s16x8 bf = *(const s16x8*)(w2_bf + (size_t)(n * 16 + lr) * HD + kk * 32 + lg * 8);
        acc = __builtin_amdgcn_mfma_f32_16x16x32_bf16(hf[kk], bf, acc, 0, 0, 0);
      }
      int a = n * 16 + lr;
      float b2v = b2g[a];
      float meta_a = meta_all[(size_t)(t * B + b) * AD + a];
      #pragma unroll
      for (int v = 0; v < 4; v++) {
        int row = lg * 4 + v;
        int i = j0 + w * 16 + row;
        float transfer = acc[v] + b2v + b2f(g_l[gidx(w * 16 + row, 64 + a)]);
        float insert = meta_a * projv[v];
        float attv = att[n][v] + insF * insert + trF * transfer;
        attv = (attv >= 0.f) ? attv : 0.01f * attv;
        attv = fminf(fmaxf(attv, -1.f), 2.f);
        att[n][v] = attv;
        size_t hi = (((size_t)t * B + b) * C + i) * AD + a;
        __builtin_nontemporal_store(attv, att_hist + hi);
        __builtin_nontemporal_store(insert, ins_hist + hi);
        __builtin_nontemporal_store(transfer, trans_hist + hi);
      }
    }
  }
  // ---- epilogue: amean, store att_g + att-half of next siaT + rowmean ----
  float amr[4];
  {
    float s[4];
    #pragma unroll
    for (int v = 0; v < 4; v++) s[v] = att[0][v] + att[1][v] + att[2][v] + att[3][v];
    #pragma unroll
    for (int v = 0; v < 4; v++) {
      s[v] += __shfl_xor(s[v], 1, 64);
      s[v] += __shfl_xor(s[v], 2, 64);
      s[v] += __shfl_xor(s[v], 4, 64);
      s[v] += __shfl_xor(s[v], 8, 64);
      amr[v] = s[v] * (1.f / AD);
    }
    if (lr == 0) {
      #pragma unroll
      for (int v = 0; v < 4; v++) {
        am_l[w * 16 + lg * 4 + v] = amr[v];
        rowmean[(size_t)b * C + j0 + w * 16 + lg * 4 + v] = amr[v];
      }
    }
  }
  {
    f32x4* ag = (f32x4*)(att_g + (size_t)blk * 4096 + tid * 16);
    #pragma unroll
    for (int n = 0; n < 4; n++) {
      f32x4 v4;
      #pragma unroll
      for (int v = 0; v < 4; v++) v4[v] = att[n][v];
      ag[n] = v4;
      unsigned long long pk = 0;
      #pragma unroll
      for (int v = 0; v < 4; v++)
        pk |= (unsigned long long)f2b(att[n][v] * amr[v]) << (16 * v);
      *(unsigned long long*)(siaT_out + (size_t)(b * 128 + 64 + n * 16 + lr) * C + j0 + w * 16 + lg * 4) = pk;
    }
  }
  __syncthreads();
  // ---- id half of next siaT ----
  #pragma unroll
  for (int k2 = 0; k2 < 2; k2++) {
    int idx = tid + k2 * 256;
    int d = idx >> 3, part = idx & 7;
    int j = part * 8;
    s16x8 iv = *(const s16x8*)(idT_g + (size_t)(b * 64 + d) * C + j0 + j);
    s16x8 ov;
    #pragma unroll
    for (int m = 0; m < 8; m++)
      ov[m] = (short)f2b(b2f((unsigned short)iv[m]) * am_l[j + m]);
    *(s16x8*)(siaT_out + (size_t)(b * 128 + d) * C + j0 + j) = ov;
  }
}

// ---------------- final softmax ----------------
__global__ void k_softmax(const float* __restrict__ rowmean, float* __restrict__ out) {
  int b = blockIdx.x;
  __shared__ float am[C];
  __shared__ float red[256];
  int tid = threadIdx.x;
  for (int i = tid; i < C; i += 256) am[i] = rowmean[(size_t)b * C + i];
  __syncthreads();
  float mx = -1e30f;
  for (int i = tid; i < C; i += 256) mx = fmaxf(mx, am[i]);
  red[tid] = mx; __syncthreads();
  for (int s = 128; s > 0; s >>= 1) { if (tid < s) red[tid] = fmaxf(red[tid], red[tid + s]); __syncthreads(); }
  mx = red[0]; __syncthreads();
  float sm = 0.f;
  for (int i = tid; i < C; i += 256) sm += expf(am[i] - mx);
  red[tid] = sm; __syncthreads();
  for (int s = 128; s > 0; s >>= 1) { if (tid < s) red[tid] += red[tid + s]; __syncthreads(); }
  float lse = logf(red[0]) + mx;
  for (int i = tid; i < C; i += 256) out[(size_t)b * C + i] = am[i] - lse;
}

extern "C" void kernel_launch(void* const* d_in, const int* in_sizes, int n_in,
                              void* d_out, int out_size, void* d_ws, size_t ws_size,
                              hipStream_t stream) {
  const int* scene     = (const int*)d_in[0];
  const int* prog_op   = (const int*)d_in[1];
  const int* prog_arg  = (const int*)d_in[2];
  const float* aein    = (const float*)d_in[3];
  const float* aeout   = (const float*)d_in[4];
  const float* aeid    = (const float*)d_in[5];
  const float* cein    = (const float*)d_in[6];
  const float* ceout   = (const float*)d_in[7];
  const float* ceid    = (const float*)d_in[8];
  const float* att_init = (const float*)d_in[11];
  const float* aw1 = (const float*)d_in[12];
  const float* ab1 = (const float*)d_in[13];
  const float* aw2 = (const float*)d_in[14];
  const float* ab2 = (const float*)d_in[15];
  const float* mw1 = (const float*)d_in[16];
  const float* mb1 = (const float*)d_in[17];
  const float* mw2 = (const float*)d_in[18];
  const float* mb2 = (const float*)d_in[19];

  char* ws = (char*)d_ws;
  size_t off = 0;
  auto carve = [&](size_t bytes) { char* p = ws + off; off += (bytes + 255) & ~(size_t)255; return p; };
  float* proj_all  = (float*)carve((size_t)T * B * C * 4);
  float* meta_all  = (float*)carve((size_t)T * B * AD * 4 + 4096);
  float* rowmean   = (float*)carve((size_t)B * C * 4);
  float* att_g     = (float*)carve((size_t)272 * 4096 * 4);
  unsigned short* dendron_bf = (unsigned short*)carve((size_t)B * C * E * 2);
  unsigned short* axonT      = (unsigned short*)carve((size_t)B * E * C * 2);
  unsigned short* idT_g      = (unsigned short*)carve((size_t)B * 64 * C * 2);
  unsigned short* siaT       = (unsigned short*)carve((size_t)B * 128 * C * 2);
  unsigned long long* Mt64   = (unsigned long long*)carve((size_t)B * 4096 * 8);
  unsigned short* w1_bf      = (unsigned short*)carve((size_t)HD * E * 2);
  unsigned short* w2_bf      = (unsigned short*)carve((size_t)AD * HD * 2);
  unsigned*       mflag      = (unsigned*)carve(1024);

  float* out_sm     = (float*)d_out;
  float* att_hist   = out_sm + B * C;
  float* ins_hist   = att_hist + (size_t)T * B * C * AD;
  float* trans_hist = ins_hist + (size_t)T * B * C * AD;

  k_setup<<<dim3(9177), dim3(256), 0, stream>>>(scene, aein, aeout, aeid, cein, ceout, ceid,
                                                att_init, prog_op, prog_arg,
                                                aw1, aw2, mw1, mb1, mw2, mb2,
                                                dendron_bf, w1_bf, w2_bf,
                                                axonT, idT_g, siaT, att_g,
                                                meta_all, proj_all, mflag);
  for (int t = 0; t < T; t++) {
    k_step<<<dim3(272), dim3(256), 0, stream>>>(t, dendron_bf, axonT, idT_g, siaT,
                                                w1_bf, ab1, w2_bf, ab2,
                                                proj_all, meta_all, prog_op,
                                                Mt64, att_g, siaT, rowmean,
                                                att_hist, ins_hist, trans_hist, mflag);
  }
  k_softmax<<<dim3(B), dim3(256), 0, stream>>>(rowmean, out_sm);
}

// Round 13
// 647.316 us; speedup vs baseline: 4.7969x; 1.0564x over previous
//
#include <hip/hip_runtime.h>

#define B 8
#define NOBJ 128
#define NATTR 4
#define T 12
#define MC 2048
#define E 128
#define IDD 64
#define AD 64
#define HD 256
#define C 2176

typedef short s16x8 __attribute__((ext_vector_type(8)));
typedef float f32x4 __attribute__((ext_vector_type(4)));

__device__ inline unsigned short f2b(float f) {
  union { float f; unsigned u; } v; v.f = f;
  unsigned r = v.u + 0x7FFFu + ((v.u >> 16) & 1u);
  return (unsigned short)(r >> 16);
}
__device__ inline float b2f(unsigned short u) {
  union { unsigned u; float f; } v; v.u = ((unsigned)u) << 16;
  return v.f;
}

// coherent (MALL-routed) accessors: WRITES + flags only; fresh buffers are
// PLAIN-read after flag gating (validated R10/R11/R12 passing)
__device__ __forceinline__ void st_coh_u64(unsigned long long* p, unsigned long long v) {
  __hip_atomic_store(p, v, __ATOMIC_RELAXED, __HIP_MEMORY_SCOPE_AGENT);
}
__device__ __forceinline__ void st_coh_u32(unsigned* p, unsigned v) {
  __hip_atomic_store(p, v, __ATOMIC_RELAXED, __HIP_MEMORY_SCOPE_AGENT);
}
__device__ __forceinline__ void st_coh_f32(float* p, float v) {
  union { float f; unsigned u; } c; c.f = v;
  __hip_atomic_store((unsigned*)p, c.u, __ATOMIC_RELAXED, __HIP_MEMORY_SCOPE_AGENT);
}
__device__ __forceinline__ unsigned ld_coh_u32(const unsigned* p) {
  return __hip_atomic_load(p, __ATOMIC_RELAXED, __HIP_MEMORY_SCOPE_AGENT);
}

// LDS swizzles: XOR row bits into the 16B-slot index (conflict-free b128)
__device__ __forceinline__ int gidx(int r, int c) {   // g [64][128]
  return r * 128 + ((((c >> 3) ^ (r & 15)) << 3) | (c & 7));
}
__device__ __forceinline__ int hidx(int r, int c) {   // h [64][256]
  return r * 256 + ((((c >> 3) ^ (r & 15)) << 3) | (c & 7));
}
__device__ __forceinline__ int mtidx(int r, int c) {  // mt [128][128]
  return r * 128 + ((((c >> 3) ^ (r & 15)) << 3) | (c & 7));
}

// ---------------- setup A (no LDS): dendron build + weight cvt/transpose + flags ----
__global__ __launch_bounds__(256) void k_setupA(
    const int* __restrict__ scene,
    const float* __restrict__ aein,
    const float* __restrict__ cein,
    const float* __restrict__ aw1, const float* __restrict__ aw2,
    const float* __restrict__ mw1, const float* __restrict__ mw2,
    unsigned short* __restrict__ dendron_bf,
    unsigned short* __restrict__ w1_bf, unsigned short* __restrict__ w2_bf,
    float* __restrict__ mw1T, float* __restrict__ mw2T,
    unsigned* __restrict__ flags) {
  int blk = blockIdx.x;
  int tid = threadIdx.x;
  if (blk < 4352) {
    int gid = blk * 2 + (tid >> 7);
    int e = tid & 127;
    int b = gid / C, j = gid % C;
    float din;
    if (j < MC) {
      din = cein[j * E + e];
    } else {
      int obj = j - MC;
      float sIn = 0.f;
      for (int a = 0; a < NATTR; a++) {
        int s = scene[(b * NOBJ + obj) * NATTR + a];
        float m = (s != -1) ? 1.f : 0.f;
        sIn += aein[(s + 1) * E + e] * m;
      }
      din = sIn;
    }
    dendron_bf[(size_t)gid * E + e] = f2b(din);
  } else if (blk < 4544) {
    int i = (blk - 4352) * 256 + tid;
    if (i < HD * E)  w1_bf[i] = f2b(aw1[i]);
    if (i < AD * HD) w2_bf[i] = f2b(aw2[i]);
    if (i < 192 * HD) { int c = i / HD, k = i % HD; mw1T[c * HD + k] = mw1[k * 192 + c]; }
    if (i < HD * AD)  { int k = i / AD, a = i % AD; mw2T[k * AD + a] = mw2[a * HD + k]; }
  } else {
    for (int i = tid; i < 512; i += 256) flags[i] = 0u;
  }
}

// ---------------- setup B (LDS): transA/idT/siaT/att_g/proj + meta ----------------
__global__ __launch_bounds__(256) void k_setupB(
    const int* __restrict__ scene,
    const float* __restrict__ aeout, const float* __restrict__ aeid,
    const float* __restrict__ ceout, const float* __restrict__ ceid,
    const float* __restrict__ att_init,
    const int* __restrict__ prog_op, const int* __restrict__ prog_arg,
    const float* __restrict__ mw1T, const float* __restrict__ mb1,
    const float* __restrict__ mw2T, const float* __restrict__ mb2,
    unsigned short* __restrict__ axonT, unsigned short* __restrict__ idT_g,
    unsigned short* __restrict__ siaT, float* __restrict__ att_g,
    float* __restrict__ meta_all, float* __restrict__ proj_all) {
  int blk = blockIdx.x;
  int tid = threadIdx.x;
  __shared__ float sbuf[13952];   // 55.8 KB carve
  if (blk < 272) {
    int b = blk / 34, jc = blk % 34;
    int j0 = jc * 64;
    float* ax   = sbuf;                 // [64][129]
    float* idb  = sbuf + 64 * 129;      // [64][65]
    float* argL = idb + 64 * 65;        // [12][128]
    int lane = tid & 63, lr = lane & 15;
    float s = att_init[lane];
    s += __shfl_xor(s, 1, 64);  s += __shfl_xor(s, 2, 64);
    s += __shfl_xor(s, 4, 64);  s += __shfl_xor(s, 8, 64);
    s += __shfl_xor(s, 16, 64); s += __shfl_xor(s, 32, 64);
    float am0 = s * (1.f / AD);
    for (int i = tid; i < 64 * 128; i += 256) {
      int j = i >> 7, e = i & 127;
      int jg = j0 + j;
      float v;
      if (jg < MC) v = ceout[jg * E + e];
      else {
        int obj = jg - MC;
        v = 0.f;
        for (int a = 0; a < NATTR; a++) {
          int sc = scene[(b * NOBJ + obj) * NATTR + a];
          float m = (sc != -1) ? 1.f : 0.f;
          v += aeout[(sc + 1) * E + e] * m;
        }
      }
      ax[j * 129 + e] = v;
    }
    for (int i = tid; i < 64 * 64; i += 256) {
      int j = i >> 6, d = i & 63;
      int jg = j0 + j;
      float v;
      if (jg < MC) v = ceid[jg * IDD + d];
      else {
        int obj = jg - MC;
        v = 0.f;
        for (int a = 0; a < NATTR; a++) {
          int sc = scene[(b * NOBJ + obj) * NATTR + a];
          float m = (sc != -1) ? 1.f : 0.f;
          v += aeid[(sc + 1) * IDD + d] * m;
        }
      }
      idb[j * 65 + d] = v;
    }
    for (int i = tid; i < T * 128; i += 256) {
      int t = i >> 7, e = i & 127;
      int arg = prog_arg[b * T + t];
      argL[t * 128 + e] = ceout[arg * E + e];
    }
    __syncthreads();
    for (int i = tid; i < 128 * 64; i += 256) {
      int e = i >> 6, jj = i & 63;
      axonT[(size_t)(b * E + e) * C + j0 + jj] = f2b(ax[jj * 129 + e]);
    }
    for (int i = tid; i < 64 * 64; i += 256) {
      int d = i >> 6, jj = i & 63;
      idT_g[(size_t)(b * 64 + d) * C + j0 + jj] = f2b(idb[jj * 65 + d]);
      siaT[(size_t)(b * 128 + d) * C + j0 + jj] = f2b(idb[jj * 65 + d] * am0);
      siaT[(size_t)(b * 128 + 64 + d) * C + j0 + jj] = f2b(att_init[d] * am0);
    }
    {
      float* ag = att_g + (size_t)blk * 4096 + tid * 16;
      #pragma unroll
      for (int n = 0; n < 4; n++) {
        float v0 = att_init[n * 16 + lr];
        #pragma unroll
        for (int v = 0; v < 4; v++) ag[n * 4 + v] = v0;
      }
    }
    // proj: dot(argL[t], ax[jj]) / E for this block's 64 rows
    {
      int jj = tid & 63, tq = tid >> 6;
      #pragma unroll
      for (int sI = 0; sI < 3; sI++) {
        int t = tq + 4 * sI;
        const float* ar = argL + t * 128;
        const float* axr = ax + jj * 129;
        float acc = 0.f;
        #pragma unroll 8
        for (int e = 0; e < 128; e++) acc += axr[e] * ar[e];
        proj_all[((size_t)t * B + b) * C + j0 + jj] = acc * (1.f / E);
      }
    }
  } else {
    // meta scan (coalesced transposed weights)
    int b = blk - 272;
    float* x = sbuf;            // [192]
    float* h = sbuf + 192;      // [256]
    float* meta = h + 256;      // [64]
    if (tid < AD) meta[tid] = att_init[tid];
    __syncthreads();
    for (int t = 0; t < T; t++) {
      int arg = prog_arg[b * T + t];
      if (tid < AD) x[tid] = meta[tid];
      else if (tid < 192) x[tid] = ceout[arg * E + (tid - 64)];
      __syncthreads();
      float s = mb1[tid];
      for (int c = 0; c < 192; c++) s += x[c] * mw1T[c * HD + tid];
      h[tid] = fmaxf(s, 0.f);
      __syncthreads();
      if (tid < AD) {
        float o = mb2[tid];
        for (int k = 0; k < HD; k++) o += h[k] * mw2T[k * AD + tid];
        float m = (prog_op[b * T + t] == 0) ? 1.f : 0.f;
        float nm = m * o + (1.f - m) * meta[tid];
        meta[tid] = nm;
        meta_all[(t * B + b) * AD + tid] = nm;
      }
      __syncthreads();
    }
  }
}

// ---------------- fused per-step kernel (R7/R12 + softmax tail) ----------------
__global__ __launch_bounds__(256) void k_step(
    int t,
    const unsigned short* __restrict__ dendron_bf,
    const unsigned short* __restrict__ axonT,
    const unsigned short* __restrict__ idT_g,
    const unsigned short* __restrict__ siaT_in,
    const unsigned short* __restrict__ w1_bf, const float* __restrict__ b1g,
    const unsigned short* __restrict__ w2_bf, const float* __restrict__ b2g,
    const float* __restrict__ proj_all, const float* __restrict__ meta_all,
    const int* __restrict__ prog_op,
    unsigned long long* __restrict__ Mt64,
    float* __restrict__ att_g, unsigned short* __restrict__ siaT_out,
    float* __restrict__ rowmean, float* __restrict__ out,
    float* __restrict__ att_hist, float* __restrict__ ins_hist,
    float* __restrict__ trans_hist,
    unsigned* __restrict__ mflag, unsigned* __restrict__ sflag) {
  const int blk = blockIdx.x;
  const int b = blk / 34, ch = blk % 34, j0 = ch * 64;
  const int tid = threadIdx.x;
  const int w = tid >> 6, lane = tid & 63, lr = lane & 15, lg = lane >> 4;

  __shared__ unsigned short smem[24576];           // 48 KB overlay
  __shared__ float am_l[64];
  __shared__ float red[256];
  unsigned short* g_l = smem;                      // bytes [0,16K)
  unsigned short* mt  = smem + 8192;               // bytes [16K,48K)
  unsigned short* h_l = smem + 8192;
  float* mred = (float*)smem;                      // producer scratch [4][32][33]

  const f32x4 z = {0.f, 0.f, 0.f, 0.f};
  const unsigned ph = (unsigned)(t + 1);

  // load attention state early (independent of M)
  float att[4][4];
  {
    const f32x4* ag = (const f32x4*)(att_g + (size_t)blk * 4096 + tid * 16);
    #pragma unroll
    for (int n = 0; n < 4; n++) {
      f32x4 v4 = ag[n];
      #pragma unroll
      for (int v = 0; v < 4; v++) att[n][v] = v4[v];
    }
  }

  // ---- producers: ch<16 compute one 32x32 tile of M = siaT @ axonT^T ----
  if (ch < 16) {
    int d0 = (ch >> 2) * 32, e0 = (ch & 3) * 32;
    const unsigned short* ap0 = siaT_in + (size_t)(b * 128 + d0 + lr) * C + w * 544 + lg * 8;
    const unsigned short* ap1 = ap0 + (size_t)16 * C;
    const unsigned short* bp0 = axonT + (size_t)(b * E + e0 + lr) * C + w * 544 + lg * 8;
    const unsigned short* bp1 = bp0 + (size_t)16 * C;
    f32x4 a00 = z, a01 = z, a10 = z, a11 = z;
    #pragma unroll 4
    for (int kk = 0; kk < 17; kk++) {
      int k0 = kk * 32;
      s16x8 A0 = *(const s16x8*)(ap0 + k0);
      s16x8 A1 = *(const s16x8*)(ap1 + k0);
      s16x8 B0 = *(const s16x8*)(bp0 + k0);
      s16x8 B1 = *(const s16x8*)(bp1 + k0);
      a00 = __builtin_amdgcn_mfma_f32_16x16x32_bf16(A0, B0, a00, 0, 0, 0);
      a01 = __builtin_amdgcn_mfma_f32_16x16x32_bf16(A0, B1, a01, 0, 0, 0);
      a10 = __builtin_amdgcn_mfma_f32_16x16x32_bf16(A1, B0, a10, 0, 0, 0);
      a11 = __builtin_amdgcn_mfma_f32_16x16x32_bf16(A1, B1, a11, 0, 0, 0);
    }
    #pragma unroll
    for (int v = 0; v < 4; v++) {
      mred[(w * 32 + lg * 4 + v) * 33 + lr]           = a00[v];
      mred[(w * 32 + lg * 4 + v) * 33 + 16 + lr]      = a01[v];
      mred[(w * 32 + 16 + lg * 4 + v) * 33 + lr]      = a10[v];
      mred[(w * 32 + 16 + lg * 4 + v) * 33 + 16 + lr] = a11[v];
    }
    __syncthreads();
    {
      int r = tid >> 3, c = (tid & 7) * 4;
      float s0 = 0.f, s1 = 0.f, s2 = 0.f, s3 = 0.f;
      #pragma unroll
      for (int w4 = 0; w4 < 4; w4++) {
        const float* p = &mred[(w4 * 32 + r) * 33 + c];
        s0 += p[0]; s1 += p[1]; s2 += p[2]; s3 += p[3];
      }
      unsigned long long pk = (unsigned long long)f2b(s0)
                            | ((unsigned long long)f2b(s1) << 16)
                            | ((unsigned long long)f2b(s2) << 32)
                            | ((unsigned long long)f2b(s3) << 48);
      st_coh_u64(Mt64 + (((size_t)(b * 128 + d0 + r) * 128) + e0 + c) / 4, pk);
    }
    asm volatile("s_waitcnt vmcnt(0)" ::: "memory");
    __syncthreads();
    if (tid == 0) st_coh_u32(mflag + b * 16 + ch, ph);
  }
  // ---- all blocks: wait for this batch's 16 M-tiles ----
  if (tid < 16) {
    while (ld_coh_u32(mflag + b * 16 + tid) < ph) __builtin_amdgcn_s_sleep(1);
  }
  __syncthreads();
  // ---- stage Mt -> LDS (PLAIN cached loads; first touch misses to MALL) ----
  {
    const unsigned long long* mtp = Mt64 + (size_t)b * 4096;
    #pragma unroll
    for (int k = 0; k < 16; k++) {
      int idx = tid + k * 256;
      unsigned long long v = mtp[idx];
      int r = idx >> 5, c4 = (idx & 31) * 4;
      *(unsigned long long*)&mt[mtidx(r, c4)] = v;
    }
  }
  __syncthreads();
  // ---- phase A: g = dendron @ M / C ----
  {
    s16x8 afr[4];
    #pragma unroll
    for (int ke = 0; ke < 4; ke++)
      afr[ke] = *(const s16x8*)(dendron_bf + (size_t)(b * C + j0 + w * 16 + lr) * E + ke * 32 + lg * 8);
    #pragma unroll
    for (int n = 0; n < 8; n++) {
      f32x4 acc = z;
      #pragma unroll
      for (int ke = 0; ke < 4; ke++) {
        s16x8 bf = *(const s16x8*)&mt[mtidx(n * 16 + lr, ke * 32 + lg * 8)];
        acc = __builtin_amdgcn_mfma_f32_16x16x32_bf16(afr[ke], bf, acc, 0, 0, 0);
      }
      #pragma unroll
      for (int v = 0; v < 4; v++)
        g_l[gidx(w * 16 + lg * 4 + v, n * 16 + lr)] = f2b(acc[v] * (1.f / C));
    }
  }
  __syncthreads();
  // ---- phase B: h = relu(g @ w1^T + b1) ----
  {
    s16x8 gf[4];
    #pragma unroll
    for (int kd = 0; kd < 4; kd++)
      gf[kd] = *(const s16x8*)&g_l[gidx(w * 16 + lr, kd * 32 + lg * 8)];
    #pragma unroll
    for (int n = 0; n < 16; n++) {
      f32x4 acc = z;
      #pragma unroll
      for (int kd = 0; kd < 4; kd++) {
        s16x8 bf = *(const s16x8*)(w1_bf + (size_t)(n * 16 + lr) * E + kd * 32 + lg * 8);
        acc = __builtin_amdgcn_mfma_f32_16x16x32_bf16(gf[kd], bf, acc, 0, 0, 0);
      }
      float b1v = b1g[n * 16 + lr];
      #pragma unroll
      for (int v = 0; v < 4; v++)
        h_l[hidx(w * 16 + lg * 4 + v, n * 16 + lr)] = f2b(fmaxf(acc[v] + b1v, 0.f));
    }
  }
  __syncthreads();
  // ---- phase C: out = h @ w2^T ; update att ; hist ----
  {
    s16x8 hf[8];
    #pragma unroll
    for (int kk = 0; kk < 8; kk++)
      hf[kk] = *(const s16x8*)&h_l[hidx(w * 16 + lr, kk * 32 + lg * 8)];
    int op = prog_op[b * T + t];
    float insF = (op == 1) ? 1.f : 0.f, trF = (op == 2) ? 1.f : 0.f;
    float projv[4];
    #pragma unroll
    for (int v = 0; v < 4; v++)
      projv[v] = proj_all[(size_t)(t * B + b) * C + j0 + w * 16 + lg * 4 + v];
    #pragma unroll
    for (int n = 0; n < 4; n++) {
      f32x4 acc = z;
      #pragma unroll
      for (int kk = 0; kk < 8; kk++) {
        s16x8 bf = *(const s16x8*)(w2_bf + (size_t)(n * 16 + lr) * HD + kk * 32 + lg * 8);
        acc = __builtin_amdgcn_mfma_f32_16x16x32_bf16(hf[kk], bf, acc, 0, 0, 0);
      }
      int a = n * 16 + lr;
      float b2v = b2g[a];
      float meta_a = meta_all[(size_t)(t * B + b) * AD + a];
      #pragma unroll
      for (int v = 0; v < 4; v++) {
        int row = lg * 4 + v;
        int i = j0 + w * 16 + row;
        float transfer = acc[v] + b2v + b2f(g_l[gidx(w * 16 + row, 64 + a)]);
        float insert = meta_a * projv[v];
        float attv = att[n][v] + insF * insert + trF * transfer;
        attv = (attv >= 0.f) ? attv : 0.01f * attv;
        attv = fminf(fmaxf(attv, -1.f), 2.f);
        att[n][v] = attv;
        size_t hi = (((size_t)t * B + b) * C + i) * AD + a;
        __builtin_nontemporal_store(attv, att_hist + hi);
        __builtin_nontemporal_store(insert, ins_hist + hi);
        __builtin_nontemporal_store(transfer, trans_hist + hi);
      }
    }
  }
  // ---- epilogue: amean ----
  float amr[4];
  {
    float s[4];
    #pragma unroll
    for (int v = 0; v < 4; v++) s[v] = att[0][v] + att[1][v] + att[2][v] + att[3][v];
    #pragma unroll
    for (int v = 0; v < 4; v++) {
      s[v] += __shfl_xor(s[v], 1, 64);
      s[v] += __shfl_xor(s[v], 2, 64);
      s[v] += __shfl_xor(s[v], 4, 64);
      s[v] += __shfl_xor(s[v], 8, 64);
      amr[v] = s[v] * (1.f / AD);
    }
    if (lr == 0) {
      #pragma unroll
      for (int v = 0; v < 4; v++) am_l[w * 16 + lg * 4 + v] = amr[v];
    }
  }
  if (t < T - 1) {
    // persist att state + att-half of next siaT
    {
      f32x4* ag = (f32x4*)(att_g + (size_t)blk * 4096 + tid * 16);
      #pragma unroll
      for (int n = 0; n < 4; n++) {
        f32x4 v4;
        #pragma unroll
        for (int v = 0; v < 4; v++) v4[v] = att[n][v];
        ag[n] = v4;
        unsigned long long pk = 0;
        #pragma unroll
        for (int v = 0; v < 4; v++)
          pk |= (unsigned long long)f2b(att[n][v] * amr[v]) << (16 * v);
        *(unsigned long long*)(siaT_out + (size_t)(b * 128 + 64 + n * 16 + lr) * C + j0 + w * 16 + lg * 4) = pk;
      }
    }
    __syncthreads();   // am_l ready
    // id half of next siaT
    #pragma unroll
    for (int k2 = 0; k2 < 2; k2++) {
      int idx = tid + k2 * 256;
      int d = idx >> 3, part = idx & 7;
      int j = part * 8;
      s16x8 iv = *(const s16x8*)(idT_g + (size_t)(b * 64 + d) * C + j0 + j);
      s16x8 ov;
      #pragma unroll
      for (int m = 0; m < 8; m++)
        ov[m] = (short)f2b(b2f((unsigned short)iv[m]) * am_l[j + m]);
      *(s16x8*)(siaT_out + (size_t)(b * 128 + d) * C + j0 + j) = ov;
    }
  } else {
    // ---- last step: rowmean (coherent) + sflag + per-batch softmax tail ----
    if (lr == 0) {
      #pragma unroll
      for (int v = 0; v < 4; v++)
        st_coh_f32(rowmean + (size_t)b * C + j0 + w * 16 + lg * 4 + v, amr[v]);
    }
    asm volatile("s_waitcnt vmcnt(0)" ::: "memory");
    __syncthreads();
    if (tid == 0) st_coh_u32(sflag + b * 34 + ch, 1u);
    if (ch == 0) {
      if (tid < 34) {
        while (ld_coh_u32(sflag + b * 34 + tid) < 1u) __builtin_amdgcn_s_sleep(1);
      }
      __syncthreads();
      float* am = (float*)smem;            // 8.7 KB, smem free now
      for (int i = tid; i < C; i += 256) am[i] = rowmean[(size_t)b * C + i];
      __syncthreads();
      float mx = -1e30f;
      for (int i = tid; i < C; i += 256) mx = fmaxf(mx, am[i]);
      red[tid] = mx; __syncthreads();
      for (int s2 = 128; s2 > 0; s2 >>= 1) { if (tid < s2) red[tid] = fmaxf(red[tid], red[tid + s2]); __syncthreads(); }
      mx = red[0]; __syncthreads();
      float sm = 0.f;
      for (int i = tid; i < C; i += 256) sm += expf(am[i] - mx);
      red[tid] = sm; __syncthreads();
      for (int s2 = 128; s2 > 0; s2 >>= 1) { if (tid < s2) red[tid] += red[tid + s2]; __syncthreads(); }
      float lse = logf(red[0]) + mx;
      for (int i = tid; i < C; i += 256) out[(size_t)b * C + i] = am[i] - lse;
    }
  }
}

extern "C" void kernel_launch(void* const* d_in, const int* in_sizes, int n_in,
                              void* d_out, int out_size, void* d_ws, size_t ws_size,
                              hipStream_t stream) {
  const int* scene     = (const int*)d_in[0];
  const int* prog_op   = (const int*)d_in[1];
  const int* prog_arg  = (const int*)d_in[2];
  const float* aein    = (const float*)d_in[3];
  const float* aeout   = (const float*)d_in[4];
  const float* aeid    = (const float*)d_in[5];
  const float* cein    = (const float*)d_in[6];
  const float* ceout   = (const float*)d_in[7];
  const float* ceid    = (const float*)d_in[8];
  const float* att_init = (const float*)d_in[11];
  const float* aw1 = (const float*)d_in[12];
  const float* ab1 = (const float*)d_in[13];
  const float* aw2 = (const float*)d_in[14];
  const float* ab2 = (const float*)d_in[15];
  const float* mw1 = (const float*)d_in[16];
  const float* mb1 = (const float*)d_in[17];
  const float* mw2 = (const float*)d_in[18];
  const float* mb2 = (const float*)d_in[19];

  char* ws = (char*)d_ws;
  size_t off = 0;
  auto carve = [&](size_t bytes) { char* p = ws + off; off += (bytes + 255) & ~(size_t)255; return p; };
  float* proj_all  = (float*)carve((size_t)T * B * C * 4);
  float* meta_all  = (float*)carve((size_t)T * B * AD * 4);
  float* mw1T      = (float*)carve((size_t)192 * HD * 4);
  float* mw2T      = (float*)carve((size_t)HD * AD * 4);
  float* rowmean   = (float*)carve((size_t)B * C * 4);
  float* att_g     = (float*)carve((size_t)272 * 4096 * 4);
  unsigned short* dendron_bf = (unsigned short*)carve((size_t)B * C * E * 2);
  unsigned short* axonT      = (unsigned short*)carve((size_t)B * E * C * 2);
  unsigned short* idT_g      = (unsigned short*)carve((size_t)B * 64 * C * 2);
  unsigned short* siaT       = (unsigned short*)carve((size_t)B * 128 * C * 2);
  unsigned long long* Mt64   = (unsigned long long*)carve((size_t)B * 4096 * 8);
  unsigned short* w1_bf      = (unsigned short*)carve((size_t)HD * E * 2);
  unsigned short* w2_bf      = (unsigned short*)carve((size_t)AD * HD * 2);
  unsigned*       flags      = (unsigned*)carve(2048);
  unsigned*       mflag = flags;            // [8][16]
  unsigned*       sflag = flags + 128;      // [8][34]

  float* out_sm     = (float*)d_out;
  float* att_hist   = out_sm + B * C;
  float* ins_hist   = att_hist + (size_t)T * B * C * AD;
  float* trans_hist = ins_hist + (size_t)T * B * C * AD;

  k_setupA<<<dim3(4545), dim3(256), 0, stream>>>(scene, aein, cein, aw1, aw2, mw1, mw2,
                                                 dendron_bf, w1_bf, w2_bf, mw1T, mw2T, flags);
  k_setupB<<<dim3(280), dim3(256), 0, stream>>>(scene, aeout, aeid, ceout, ceid, att_init,
                                                prog_op, prog_arg, mw1T, mb1, mw2T, mb2,
                                                axonT, idT_g, siaT, att_g,
                                                meta_all, proj_all);
  for (int t = 0; t < T; t++) {
    k_step<<<dim3(272), dim3(256), 0, stream>>>(t, dendron_bf, axonT, idT_g, siaT,
                                                w1_bf, ab1, w2_bf, ab2,
                                                proj_all, meta_all, prog_op,
                                                Mt64, att_g, siaT, rowmean, out_sm,
                                                att_hist, ins_hist, trans_hist,
                                                mflag, sflag);
  }
}